// Round 5
// baseline (1413.861 us; speedup 1.0000x reference)
//
#include <hip/hip_runtime.h>
#include <hip/hip_bf16.h>

#define BB 16
#define SS 512
#define DD 1024
#define HH 16
#define LL 4
#define DHH 64
#define GK 1024
#define GN 1024

typedef __attribute__((ext_vector_type(8))) short short8;
typedef __attribute__((ext_vector_type(4))) float f32x4;

__device__ __forceinline__ unsigned short f2bf(float f) {
  union { float f; unsigned int u; } v; v.f = f;
  unsigned int r = v.u + 0x7FFFu + ((v.u >> 16) & 1u);
  return (unsigned short)(r >> 16);
}

__device__ __forceinline__ float wave_max(float v) {
#pragma unroll
  for (int off = 32; off > 0; off >>= 1) v = fmaxf(v, __shfl_xor(v, off));
  return v;
}
__device__ __forceinline__ float wave_sum(float v) {
#pragma unroll
  for (int off = 32; off > 0; off >>= 1) v += __shfl_xor(v, off);
  return v;
}

// global -> LDS direct 16B copy (CK-style addrspace reinterpret).
// LDS dest is wave-uniform base + lane*16 (per-lane dest bits ignored).
__device__ __forceinline__ void gl16(const void* g, void* l) {
  __builtin_amdgcn_global_load_lds(
      (const __attribute__((address_space(1))) unsigned int*)(uintptr_t)g,
      (__attribute__((address_space(3))) unsigned int*)(unsigned int)(uintptr_t)l,
      16, 0, 0);
}

// ---------------- weights fp32 -> bf16 ----------------
__global__ __launch_bounds__(256) void k_w2bf(const float* __restrict__ w,
                                              unsigned short* __restrict__ o) {
  size_t i4 = ((size_t)blockIdx.x * 256 + threadIdx.x) * 4;
  float4 v = *(const float4*)(w + i4);
  uint2 pk;
  pk.x = (unsigned)f2bf(v.x) | ((unsigned)f2bf(v.y) << 16);
  pk.y = (unsigned)f2bf(v.z) | ((unsigned)f2bf(v.w) << 16);
  *(uint2*)(o + i4) = pk;
}

// ---------------- q0 = x + positional encoding (fp32 + bf16 shadow) ----------------
__global__ __launch_bounds__(256) void k_add_pe(const float* __restrict__ x,
                                                float* __restrict__ out,
                                                unsigned short* __restrict__ outb) {
  size_t i4 = ((size_t)blockIdx.x * 256 + threadIdx.x) * 4;
  int d0 = (int)(i4 & (DD - 1));
  int s = (int)((i4 >> 10) & (SS - 1));
  float4 xv = *(const float4*)(x + i4);
  int ip0 = d0 >> 1;
  float f0 = __expf((float)ip0 * -0.017988946039016f);
  float f1 = __expf((float)(ip0 + 1) * -0.017988946039016f);
  float s0v, c0v, s1v, c1v;
  __sincosf((float)s * f0, &s0v, &c0v);
  __sincosf((float)s * f1, &s1v, &c1v);
  float4 o;
  o.x = xv.x + s0v; o.y = xv.y + c0v; o.z = xv.z + s1v; o.w = xv.w + c1v;
  *(float4*)(out + i4) = o;
  uint2 pk;
  pk.x = (unsigned)f2bf(o.x) | ((unsigned)f2bf(o.y) << 16);
  pk.y = (unsigned)f2bf(o.z) | ((unsigned)f2bf(o.w) << 16);
  *(uint2*)(outb + i4) = pk;
}

// ---------------- C = A[M,K]bf16 @ W[N,K]^T bf16 + bias ----------------
// m97 structure: 128x128 tile, 4 waves (2x2), BK=32, global_load_lds 16B.
// MODE 0: bf16 [M,N] out.  MODE 1: bf16 transposed [b, col, s] out.  MODE 2: fp32 [M,N].
template <int MODE>
__global__ __launch_bounds__(256) void k_gemm(
    const unsigned short* __restrict__ A, const unsigned short* __restrict__ W,
    const float* __restrict__ bias, void* __restrict__ out) {
  __shared__ unsigned short As[128 * 32];
  __shared__ unsigned short Bs[128 * 32];
  const int tid = threadIdx.x;
  const int lane = tid & 63;
  const int w = tid >> 6;
  const int wr = w >> 1, wc = w & 1;
  const int fr = lane & 15, fq = lane >> 4;

  // XCD swizzle: 512 wgs = 8 XCDs x 64; each XCD owns one N-panel sweep
  int bid = blockIdx.x;
  bid = (bid & 7) * 64 + (bid >> 3);
  const int bm = (bid & 63) * 128;
  const int bn = (bid >> 6) * 128;

  f32x4 acc[4][4] = {};

  const unsigned short* ga = A + (size_t)(bm + w * 16 + (lane >> 2)) * GK + (lane & 3) * 8;
  const unsigned short* gb = W + (size_t)(bn + w * 16 + (lane >> 2)) * GK + (lane & 3) * 8;
  unsigned short* la = As + w * 512;   // wave-uniform LDS base
  unsigned short* lb = Bs + w * 512;

  for (int k0 = 0; k0 < GK; k0 += 32) {
    gl16(ga + k0, la);
    gl16(ga + 64 * GK + k0, la + 2048);
    gl16(gb + k0, lb);
    gl16(gb + 64 * GK + k0, lb + 2048);
    __syncthreads();
    short8 af[4], bf[4];
#pragma unroll
    for (int m = 0; m < 4; ++m)
      af[m] = *(const short8*)(As + (wr * 64 + m * 16 + fr) * 32 + fq * 8);
#pragma unroll
    for (int n = 0; n < 4; ++n)
      bf[n] = *(const short8*)(Bs + (wc * 64 + n * 16 + fr) * 32 + fq * 8);
#pragma unroll
    for (int m = 0; m < 4; ++m)
#pragma unroll
      for (int n = 0; n < 4; ++n)
        acc[m][n] = __builtin_amdgcn_mfma_f32_16x16x32_bf16(af[m], bf[n], acc[m][n], 0, 0, 0);
    __syncthreads();
  }

#pragma unroll
  for (int m = 0; m < 4; ++m) {
    const int row0 = bm + wr * 64 + m * 16 + fq * 4;
#pragma unroll
    for (int n = 0; n < 4; ++n) {
      const int col = bn + wc * 64 + n * 16 + fr;
      const float bsv = bias[col];
      if constexpr (MODE == 0) {
        unsigned short* o = (unsigned short*)out;
#pragma unroll
        for (int r = 0; r < 4; ++r)
          o[(size_t)(row0 + r) * GN + col] = f2bf(acc[m][n][r] + bsv);
      } else if constexpr (MODE == 1) {
        unsigned short* o = (unsigned short*)out;
        const int bi = row0 >> 9, si = row0 & (SS - 1);
        uint2 pk;
        pk.x = (unsigned)f2bf(acc[m][n][0] + bsv) | ((unsigned)f2bf(acc[m][n][1] + bsv) << 16);
        pk.y = (unsigned)f2bf(acc[m][n][2] + bsv) | ((unsigned)f2bf(acc[m][n][3] + bsv) << 16);
        *(uint2*)(o + ((size_t)bi * DD + col) * SS + si) = pk;
      } else {
        float* o = (float*)out;
#pragma unroll
        for (int r = 0; r < 4; ++r)
          o[(size_t)(row0 + r) * GN + col] = acc[m][n][r] + bsv;
      }
    }
  }
}

// ---------------- fused MFMA attention (bf16 inputs) ----------------
// Block: one (b,h), 32-row i-tile, 8 waves. Q/K from bf16 qlin [b,s,D];
// V from transposed bf16 Vt [b, dcol, s]. LDS 78 KB -> 2 blocks/CU.
// Softmax chain uses STRIDED lane->j mapping (j = c*64+lane, c < njt):
// work scales with the tile's real j-extent (avg 288 vs 512) and all
// score LDS accesses are lane-consecutive (conflict-free).
__global__ __launch_bounds__(512) void k_attn_mfma(
    const unsigned short* __restrict__ Q, const unsigned short* __restrict__ Vt,
    const float* __restrict__ gam, unsigned short* __restrict__ AO,
    float* __restrict__ scores_out) {
  __shared__ float sc_s[32][516];          // 66048 B
  __shared__ unsigned short Qs[32][72];    //  4608 B
  __shared__ unsigned short KV[64][72];    //  9216 B (K tile, then V^T tile)

  const int tid = threadIdx.x;
  const int lane = tid & 63;
  const int w = tid >> 6;
  const int wr = w & 1;
  const int wc = w >> 1;
  const int fr = lane & 15, fq = lane >> 4;

  const int itile = blockIdx.x & 15;
  const int bh = blockIdx.x >> 4;
  const int b = bh >> 4;
  const int h = bh & 15;
  const int i0 = itile * 32;
  const int njt = (itile + 2) >> 1;
  const int jcap = njt * 64;
  (void)jcap;

  const unsigned short* Qb = Q + (size_t)b * SS * DD + h * DHH;
  const unsigned short* Vtb = Vt + ((size_t)b * DD + h * DHH) * SS;
  const float gneg = -fabsf(gam[h]);

  const int srow = tid >> 3;             // 0..63
  const int sdb = (tid & 7) * 8;

  if (tid < 256) {
    const int qr = tid >> 3, qc = (tid & 7) * 8;
    *(short8*)&Qs[qr][qc] = *(const short8*)(Qb + (size_t)(i0 + qr) * DD + qc);
  }

  // ---- QK^T into sc_s (scaled + causally masked) ----
  for (int jt = 0; jt < njt; ++jt) {
    *(short8*)&KV[srow][sdb] = *(const short8*)(Qb + (size_t)(jt * 64 + srow) * DD + sdb);
    __syncthreads();

    short8 a0 = *(const short8*)&Qs[wr * 16 + fr][fq * 8];
    short8 a1 = *(const short8*)&Qs[wr * 16 + fr][32 + fq * 8];
    short8 b0 = *(const short8*)&KV[wc * 16 + fr][fq * 8];
    short8 b1 = *(const short8*)&KV[wc * 16 + fr][32 + fq * 8];
    f32x4 s0 = {};
    s0 = __builtin_amdgcn_mfma_f32_16x16x32_bf16(a0, b0, s0, 0, 0, 0);
    s0 = __builtin_amdgcn_mfma_f32_16x16x32_bf16(a1, b1, s0, 0, 0, 0);

    const int j = jt * 64 + wc * 16 + fr;
#pragma unroll
    for (int r = 0; r < 4; ++r) {
      const int row = wr * 16 + fq * 4 + r;
      sc_s[row][j] = (j < i0 + row) ? s0[r] * 0.125f : -1e30f;
    }
    __syncthreads();
  }

  // ---- softmax -> cumsum -> dist-decay -> softmax -> maxout, per row ----
  // lane owns j = c*64 + lane for c < njt (strided, conflict-free).
  for (int q = 0; q < 4; ++q) {
    const int r_i = w * 4 + q;
    const int gi = i0 + r_i;
    const float* rowp = &sc_s[r_i][0];
    float sc[8], p[8], cum[8];

    float m1l = -3e38f;
#pragma unroll
    for (int c = 0; c < 8; ++c)
      if (c < njt) {
        sc[c] = rowp[c * 64 + lane];
        m1l = fmaxf(m1l, sc[c]);
      }
    const float m1 = wave_max(m1l);

    float base = 0.0f;
#pragma unroll
    for (int c = 0; c < 8; ++c)
      if (c < njt) {
        float x = __expf(sc[c] - m1);
        p[c] = x;
#pragma unroll
        for (int off = 1; off < 64; off <<= 1) {
          float y = __shfl_up(x, off);
          if (lane >= off) x += y;
        }
        cum[c] = base + x;              // inclusive cumsum at j = c*64+lane
        base += __shfl(x, 63);          // chunk total
      }
    const float inv = 1.0f / base;      // base == row total

    float m2l = -3e38f;
#pragma unroll
    for (int c = 0; c < 8; ++c)
      if (c < njt) {
        const float cm = cum[c] * inv;
        const int j = c * 64 + lane;
        const float dist = sqrtf(fmaxf((1.0f - cm) * (float)(gi - j), 0.0f));
        float te = __expf(gneg * dist);
        te = fminf(fmaxf(te, 1e-5f), 1e5f);
        const float s2v = sc[c] * te;
        sc[c] = s2v;
        m2l = fmaxf(m2l, s2v);
      }
    const float m2 = wave_max(m2l);

    float ls2 = 0.0f;
#pragma unroll
    for (int c = 0; c < 8; ++c)
      if (c < njt) {
        p[c] = __expf(sc[c] - m2);
        ls2 += p[c];
      }
    const float tot2 = wave_sum(ls2);
    const float mult = fminf(tot2, 5.0f) / tot2;

    unsigned short* brow = (unsigned short*)&sc_s[r_i][0];
    float* so = scores_out
                    ? scores_out + ((size_t)(b * HH + h) * SS + gi) * SS
                    : nullptr;
#pragma unroll
    for (int c = 0; c < 8; ++c) {
      float av = 0.0f;
      if (c < njt) {
        av = (gi == 0) ? 0.0f : p[c] * mult;
        brow[c * 64 + lane] = f2bf(av);
      }
      if (so) so[c * 64 + lane] = av;   // c >= njt: zero-fill tail
    }
  }
  __syncthreads();

  // ---- PV: out[i,d] = sum_j attn[i,j] * V[j,d]; V^T tile from Vt global ----
  f32x4 o0 = {};
  for (int jt = 0; jt < njt; ++jt) {
    *(short8*)&KV[srow][sdb] =
        *(const short8*)(Vtb + (size_t)srow * SS + jt * 64 + sdb);
    __syncthreads();

    const unsigned short* arow = (const unsigned short*)&sc_s[wr * 16 + fr][0];
    short8 a0 = *(const short8*)(arow + jt * 64 + fq * 8);
    short8 a1 = *(const short8*)(arow + jt * 64 + 32 + fq * 8);
    short8 b0 = *(const short8*)&KV[wc * 16 + fr][fq * 8];
    short8 b1 = *(const short8*)&KV[wc * 16 + fr][32 + fq * 8];
    o0 = __builtin_amdgcn_mfma_f32_16x16x32_bf16(a0, b0, o0, 0, 0, 0);
    o0 = __builtin_amdgcn_mfma_f32_16x16x32_bf16(a1, b1, o0, 0, 0, 0);
    __syncthreads();
  }

  {
    const int d = h * DHH + wc * 16 + fr;
#pragma unroll
    for (int r = 0; r < 4; ++r) {
      const int row = i0 + wr * 16 + fq * 4 + r;
      AO[((size_t)b * SS + row) * DD + d] = f2bf(o0[r]);
    }
  }
}

// ---------------- residual + layernorm (fp32 out, optional bf16 shadow) ----------------
__global__ __launch_bounds__(256) void k_res_ln(
    const float* __restrict__ x, const float* __restrict__ r,
    const float* __restrict__ w, const float* __restrict__ b,
    float* __restrict__ out, unsigned short* __restrict__ outb) {
  __shared__ float red[4];
  const int row = blockIdx.x;
  const int tid = threadIdx.x;
  const int lane = tid & 63, wv = tid >> 6;
  float4 y = ((const float4*)(x + (size_t)row * DD))[tid];
  if (r) {
    float4 rr = ((const float4*)(r + (size_t)row * DD))[tid];
    y.x += rr.x; y.y += rr.y; y.z += rr.z; y.w += rr.w;
  }
  float s = y.x + y.y + y.z + y.w;
  s = wave_sum(s);
  if (lane == 0) red[wv] = s;
  __syncthreads();
  float mean = (red[0] + red[1] + red[2] + red[3]) * (1.0f / DD);
  __syncthreads();
  float d0 = y.x - mean, d1 = y.y - mean, d2 = y.z - mean, d3 = y.w - mean;
  float s2 = d0 * d0 + d1 * d1 + d2 * d2 + d3 * d3;
  s2 = wave_sum(s2);
  if (lane == 0) red[wv] = s2;
  __syncthreads();
  float var = (red[0] + red[1] + red[2] + red[3]) * (1.0f / DD);
  float rstd = rsqrtf(var + 1e-5f);
  float4 ww = ((const float4*)w)[tid];
  float4 bb = ((const float4*)b)[tid];
  float4 o;
  o.x = d0 * rstd * ww.x + bb.x;
  o.y = d1 * rstd * ww.y + bb.y;
  o.z = d2 * rstd * ww.z + bb.z;
  o.w = d3 * rstd * ww.w + bb.w;
  ((float4*)(out + (size_t)row * DD))[tid] = o;
  if (outb) {
    uint2 pk;
    pk.x = (unsigned)f2bf(o.x) | ((unsigned)f2bf(o.y) << 16);
    pk.y = (unsigned)f2bf(o.z) | ((unsigned)f2bf(o.w) << 16);
    *(uint2*)(outb + (size_t)row * DD + tid * 4) = pk;
  }
}

extern "C" void kernel_launch(void* const* d_in, const int* in_sizes, int n_in,
                              void* d_out, int out_size, void* d_ws, size_t ws_size,
                              hipStream_t stream) {
  (void)in_sizes; (void)n_in; (void)out_size; (void)ws_size;
  const float* x = (const float*)d_in[0];
  const float* Wq = (const float*)d_in[2];
  const float* bq = (const float*)d_in[3];
  const float* Wv = (const float*)d_in[4];
  const float* bv = (const float*)d_in[5];
  const float* Wo = (const float*)d_in[6];
  const float* bo = (const float*)d_in[7];
  const float* gam = (const float*)d_in[8];
  const float* lnw = (const float*)d_in[9];
  const float* lnb = (const float*)d_in[10];
  const float* flnw = (const float*)d_in[11];
  const float* flnb = (const float*)d_in[12];

  float* out0 = (float*)d_out;
  float* scores = out0 + (size_t)BB * SS * DD;
  const size_t BUF = (size_t)BB * SS * DD;       // 8.4M elems
  const size_t WSZ = (size_t)LL * DD * DD;       // 4.2M elems per weight set
  const size_t BHSS = (size_t)BB * HH * SS * SS; // 67.1M floats (scores)

  float* P0 = (float*)d_ws;
  float* P1 = P0 + BUF;
  unsigned short* us = (unsigned short*)(P1 + BUF);
  unsigned short* Abf = us;
  unsigned short* Qbf = us + BUF;
  unsigned short* VtB = us + 2 * BUF;
  unsigned short* AObf = us + 3 * BUF;
  unsigned short* Wob = us + 4 * BUF;            // ws total ~142.6 MB
  // Wq/Wv bf16 live at the tail of the scores region of d_out: their last
  // use (layer-3 q/v GEMMs) precedes the layer-3 attention that overwrites
  // the whole scores region with the real output.
  unsigned short* Wqb = (unsigned short*)scores + (2 * BHSS - 2 * WSZ);
  unsigned short* Wvb = Wqb + WSZ;

  const int M = BB * SS;  // 8192

  k_w2bf<<<dim3(WSZ / 1024), 256, 0, stream>>>(Wq, Wqb);
  k_w2bf<<<dim3(WSZ / 1024), 256, 0, stream>>>(Wv, Wvb);
  k_w2bf<<<dim3(WSZ / 1024), 256, 0, stream>>>(Wo, Wob);
  k_add_pe<<<dim3(BUF / 1024), 256, 0, stream>>>(x, P0, Abf);

  float* Acur = P0;
  float* Pnx = P1;
  for (int l = 0; l < LL; ++l) {
    k_gemm<0><<<dim3(512), 256, 0, stream>>>(Abf, Wqb + (size_t)l * DD * DD, bq + l * DD, Qbf);
    k_gemm<1><<<dim3(512), 256, 0, stream>>>(Abf, Wvb + (size_t)l * DD * DD, bv + l * DD, VtB);
    k_attn_mfma<<<dim3(BB * HH * (SS / 32)), 512, 0, stream>>>(
        Qbf, VtB, gam + l * HH, AObf, (l == LL - 1) ? scores : nullptr);
    k_gemm<2><<<dim3(512), 256, 0, stream>>>(AObf, Wob + (size_t)l * DD * DD, bo + l * DD, Pnx);
    k_res_ln<<<dim3(M), 256, 0, stream>>>(Acur, Pnx, lnw + l * DD, lnb + l * DD, Pnx, Abf);
    float* t = Acur; Acur = Pnx; Pnx = t;
  }
  k_res_ln<<<dim3(M), 256, 0, stream>>>(Acur, nullptr, flnw, flnb, out0, nullptr);
}

// Round 6
// 1237.031 us; speedup vs baseline: 1.1429x; 1.1429x over previous
//
#include <hip/hip_runtime.h>
#include <hip/hip_bf16.h>

#define BB 16
#define SS 512
#define DD 1024
#define HH 16
#define LL 4
#define DHH 64
#define GK 1024
#define GN 1024

typedef __attribute__((ext_vector_type(8))) short short8;
typedef __attribute__((ext_vector_type(4))) float f32x4;

__device__ __forceinline__ unsigned short f2bf(float f) {
  union { float f; unsigned int u; } v; v.f = f;
  unsigned int r = v.u + 0x7FFFu + ((v.u >> 16) & 1u);
  return (unsigned short)(r >> 16);
}

__device__ __forceinline__ float wave_max(float v) {
#pragma unroll
  for (int off = 32; off > 0; off >>= 1) v = fmaxf(v, __shfl_xor(v, off));
  return v;
}
__device__ __forceinline__ float wave_sum(float v) {
#pragma unroll
  for (int off = 32; off > 0; off >>= 1) v += __shfl_xor(v, off);
  return v;
}

// global -> LDS direct 16B copy (CK-style addrspace reinterpret).
// LDS dest is wave-uniform base + lane*16 (per-lane dest bits ignored).
__device__ __forceinline__ void gl16(const void* g, void* l) {
  __builtin_amdgcn_global_load_lds(
      (const __attribute__((address_space(1))) unsigned int*)(uintptr_t)g,
      (__attribute__((address_space(3))) unsigned int*)(unsigned int)(uintptr_t)l,
      16, 0, 0);
}

// ---------------- weights fp32 -> bf16 ----------------
__global__ __launch_bounds__(256) void k_w2bf(const float* __restrict__ w,
                                              unsigned short* __restrict__ o) {
  size_t i4 = ((size_t)blockIdx.x * 256 + threadIdx.x) * 4;
  float4 v = *(const float4*)(w + i4);
  uint2 pk;
  pk.x = (unsigned)f2bf(v.x) | ((unsigned)f2bf(v.y) << 16);
  pk.y = (unsigned)f2bf(v.z) | ((unsigned)f2bf(v.w) << 16);
  *(uint2*)(o + i4) = pk;
}

// ---------------- q0 = x + positional encoding (fp32 + bf16 shadow) ----------------
__global__ __launch_bounds__(256) void k_add_pe(const float* __restrict__ x,
                                                float* __restrict__ out,
                                                unsigned short* __restrict__ outb) {
  size_t i4 = ((size_t)blockIdx.x * 256 + threadIdx.x) * 4;
  int d0 = (int)(i4 & (DD - 1));
  int s = (int)((i4 >> 10) & (SS - 1));
  float4 xv = *(const float4*)(x + i4);
  int ip0 = d0 >> 1;
  float f0 = __expf((float)ip0 * -0.017988946039016f);
  float f1 = __expf((float)(ip0 + 1) * -0.017988946039016f);
  float s0v, c0v, s1v, c1v;
  __sincosf((float)s * f0, &s0v, &c0v);
  __sincosf((float)s * f1, &s1v, &c1v);
  float4 o;
  o.x = xv.x + s0v; o.y = xv.y + c0v; o.z = xv.z + s1v; o.w = xv.w + c1v;
  *(float4*)(out + i4) = o;
  uint2 pk;
  pk.x = (unsigned)f2bf(o.x) | ((unsigned)f2bf(o.y) << 16);
  pk.y = (unsigned)f2bf(o.z) | ((unsigned)f2bf(o.w) << 16);
  *(uint2*)(outb + i4) = pk;
}

// ---------------- C = A[M,K]bf16 @ W[N,K]^T bf16 + bias ----------------
// m97 structure: 128x128 tile, 4 waves (2x2), BK=32, global_load_lds 16B.
// MODE 0: bf16 [M,N] out.  MODE 1: bf16 transposed [b, col, s] out.  MODE 2: fp32 [M,N].
template <int MODE>
__global__ __launch_bounds__(256) void k_gemm(
    const unsigned short* __restrict__ A, const unsigned short* __restrict__ W,
    const float* __restrict__ bias, void* __restrict__ out) {
  __shared__ unsigned short As[128 * 32];
  __shared__ unsigned short Bs[128 * 32];
  const int tid = threadIdx.x;
  const int lane = tid & 63;
  const int w = tid >> 6;
  const int wr = w >> 1, wc = w & 1;
  const int fr = lane & 15, fq = lane >> 4;

  // XCD swizzle: 512 wgs = 8 XCDs x 64; each XCD owns one N-panel sweep
  int bid = blockIdx.x;
  bid = (bid & 7) * 64 + (bid >> 3);
  const int bm = (bid & 63) * 128;
  const int bn = (bid >> 6) * 128;

  f32x4 acc[4][4] = {};

  const unsigned short* ga = A + (size_t)(bm + w * 16 + (lane >> 2)) * GK + (lane & 3) * 8;
  const unsigned short* gb = W + (size_t)(bn + w * 16 + (lane >> 2)) * GK + (lane & 3) * 8;
  unsigned short* la = As + w * 512;   // wave-uniform LDS base
  unsigned short* lb = Bs + w * 512;

  for (int k0 = 0; k0 < GK; k0 += 32) {
    gl16(ga + k0, la);
    gl16(ga + 64 * GK + k0, la + 2048);
    gl16(gb + k0, lb);
    gl16(gb + 64 * GK + k0, lb + 2048);
    __syncthreads();
    short8 af[4], bf[4];
#pragma unroll
    for (int m = 0; m < 4; ++m)
      af[m] = *(const short8*)(As + (wr * 64 + m * 16 + fr) * 32 + fq * 8);
#pragma unroll
    for (int n = 0; n < 4; ++n)
      bf[n] = *(const short8*)(Bs + (wc * 64 + n * 16 + fr) * 32 + fq * 8);
#pragma unroll
    for (int m = 0; m < 4; ++m)
#pragma unroll
      for (int n = 0; n < 4; ++n)
        acc[m][n] = __builtin_amdgcn_mfma_f32_16x16x32_bf16(af[m], bf[n], acc[m][n], 0, 0, 0);
    __syncthreads();
  }

#pragma unroll
  for (int m = 0; m < 4; ++m) {
    const int row0 = bm + wr * 64 + m * 16 + fq * 4;
#pragma unroll
    for (int n = 0; n < 4; ++n) {
      const int col = bn + wc * 64 + n * 16 + fr;
      const float bsv = bias[col];
      if constexpr (MODE == 0) {
        unsigned short* o = (unsigned short*)out;
#pragma unroll
        for (int r = 0; r < 4; ++r)
          o[(size_t)(row0 + r) * GN + col] = f2bf(acc[m][n][r] + bsv);
      } else if constexpr (MODE == 1) {
        unsigned short* o = (unsigned short*)out;
        const int bi = row0 >> 9, si = row0 & (SS - 1);
        uint2 pk;
        pk.x = (unsigned)f2bf(acc[m][n][0] + bsv) | ((unsigned)f2bf(acc[m][n][1] + bsv) << 16);
        pk.y = (unsigned)f2bf(acc[m][n][2] + bsv) | ((unsigned)f2bf(acc[m][n][3] + bsv) << 16);
        *(uint2*)(o + ((size_t)bi * DD + col) * SS + si) = pk;
      } else {
        float* o = (float*)out;
#pragma unroll
        for (int r = 0; r < 4; ++r)
          o[(size_t)(row0 + r) * GN + col] = acc[m][n][r] + bsv;
      }
    }
  }
}

// ---------------- fused MFMA attention (bf16 inputs) ----------------
// Block: one (b,h), 32-row i-tile, 8 waves. Q/K from bf16 qlin [b,s,D];
// V from transposed bf16 Vt [b, dcol, s]. LDS 78 KB -> 2 blocks/CU.
// Softmax: lane owns a CONTIGUOUS chunk of njt elements (j = lane*njt + c),
// so work scales with the tile's j-extent while the cumsum keeps the
// round-4 short-scan structure (local prefix + ONE 6-step shfl scan).
__global__ __launch_bounds__(512) void k_attn_mfma(
    const unsigned short* __restrict__ Q, const unsigned short* __restrict__ Vt,
    const float* __restrict__ gam, unsigned short* __restrict__ AO,
    float* __restrict__ scores_out) {
  __shared__ float sc_s[32][516];          // 66048 B
  __shared__ unsigned short Qs[32][72];    //  4608 B
  __shared__ unsigned short KV[64][72];    //  9216 B (K tile, then V^T tile)

  const int tid = threadIdx.x;
  const int lane = tid & 63;
  const int w = tid >> 6;
  const int wr = w & 1;
  const int wc = w >> 1;
  const int fr = lane & 15, fq = lane >> 4;

  const int itile = blockIdx.x & 15;
  const int bh = blockIdx.x >> 4;
  const int b = bh >> 4;
  const int h = bh & 15;
  const int i0 = itile * 32;
  const int njt = (itile + 2) >> 1;        // 64-col j-tiles (1..8)
  const int jcap = njt * 64;

  const unsigned short* Qb = Q + (size_t)b * SS * DD + h * DHH;
  const unsigned short* Vtb = Vt + ((size_t)b * DD + h * DHH) * SS;
  const float gneg = -fabsf(gam[h]);

  const int srow = tid >> 3;             // 0..63
  const int sdb = (tid & 7) * 8;

  if (tid < 256) {
    const int qr = tid >> 3, qc = (tid & 7) * 8;
    *(short8*)&Qs[qr][qc] = *(const short8*)(Qb + (size_t)(i0 + qr) * DD + qc);
  }

  // ---- QK^T into sc_s (scaled + causally masked) ----
  for (int jt = 0; jt < njt; ++jt) {
    *(short8*)&KV[srow][sdb] = *(const short8*)(Qb + (size_t)(jt * 64 + srow) * DD + sdb);
    __syncthreads();

    short8 a0 = *(const short8*)&Qs[wr * 16 + fr][fq * 8];
    short8 a1 = *(const short8*)&Qs[wr * 16 + fr][32 + fq * 8];
    short8 b0 = *(const short8*)&KV[wc * 16 + fr][fq * 8];
    short8 b1 = *(const short8*)&KV[wc * 16 + fr][32 + fq * 8];
    f32x4 s0 = {};
    s0 = __builtin_amdgcn_mfma_f32_16x16x32_bf16(a0, b0, s0, 0, 0, 0);
    s0 = __builtin_amdgcn_mfma_f32_16x16x32_bf16(a1, b1, s0, 0, 0, 0);

    const int j = jt * 64 + wc * 16 + fr;
#pragma unroll
    for (int r = 0; r < 4; ++r) {
      const int row = wr * 16 + fq * 4 + r;
      sc_s[row][j] = (j < i0 + row) ? s0[r] * 0.125f : -1e30f;
    }
    __syncthreads();
  }

  // ---- softmax -> cumsum -> dist-decay -> softmax -> maxout, per row ----
  // lane owns contiguous j in [lane*njt, (lane+1)*njt); work scales w/ jcap.
  for (int q = 0; q < 4; ++q) {
    const int r_i = w * 4 + q;
    const int gi = i0 + r_i;
    const float* rowp = &sc_s[r_i][0];
    const int jb = lane * njt;
    float sc[8], p[8];

    float m1l = -3e38f;
#pragma unroll
    for (int c = 0; c < 8; ++c)
      if (c < njt) {
        sc[c] = rowp[jb + c];
        m1l = fmaxf(m1l, sc[c]);
      }
    const float m1 = wave_max(m1l);

    float lsum = 0.0f;
#pragma unroll
    for (int c = 0; c < 8; ++c)
      if (c < njt) {
        p[c] = __expf(sc[c] - m1);
        lsum += p[c];
      }

    // single 6-step inclusive scan over lane totals; lane63 = row total
    float xs = lsum;
#pragma unroll
    for (int off = 1; off < 64; off <<= 1) {
      float y = __shfl_up(xs, off);
      if (lane >= off) xs += y;
    }
    const float tot = __shfl(xs, 63);
    const float inv = 1.0f / tot;
    float run = xs - lsum;               // exclusive prefix of lane's chunk

    float m2l = -3e38f;
#pragma unroll
    for (int c = 0; c < 8; ++c)
      if (c < njt) {
        run += p[c];
        const float cm = run * inv;
        const int j = jb + c;
        const float dist = sqrtf(fmaxf((1.0f - cm) * (float)(gi - j), 0.0f));
        float te = __expf(gneg * dist);
        te = fminf(fmaxf(te, 1e-5f), 1e5f);
        sc[c] = sc[c] * te;
        m2l = fmaxf(m2l, sc[c]);
      }
    const float m2 = wave_max(m2l);

    float ls2 = 0.0f;
#pragma unroll
    for (int c = 0; c < 8; ++c)
      if (c < njt) {
        p[c] = __expf(sc[c] - m2);
        ls2 += p[c];
      }
    const float tot2 = wave_sum(ls2);
    const float mult = fminf(tot2, 5.0f) / tot2;

    unsigned short* brow = (unsigned short*)&sc_s[r_i][0];
    float* so = scores_out
                    ? scores_out + ((size_t)(b * HH + h) * SS + gi) * SS
                    : nullptr;
#pragma unroll
    for (int c = 0; c < 8; ++c)
      if (c < njt) {
        const float av = (gi == 0) ? 0.0f : p[c] * mult;
        brow[jb + c] = f2bf(av);
        if (so) so[jb + c] = av;
      }
    if (so) {
      // zero-fill tail [jcap, 512)
#pragma unroll
      for (int c = 0; c < 8; ++c)
        if (c < 8 - njt) so[jcap + c * 64 + lane] = 0.0f;
    }
  }
  __syncthreads();

  // ---- PV: out[i,d] = sum_j attn[i,j] * V[j,d]; V^T tile from Vt global ----
  f32x4 o0 = {};
  for (int jt = 0; jt < njt; ++jt) {
    *(short8*)&KV[srow][sdb] =
        *(const short8*)(Vtb + (size_t)srow * SS + jt * 64 + sdb);
    __syncthreads();

    const unsigned short* arow = (const unsigned short*)&sc_s[wr * 16 + fr][0];
    short8 a0 = *(const short8*)(arow + jt * 64 + fq * 8);
    short8 a1 = *(const short8*)(arow + jt * 64 + 32 + fq * 8);
    short8 b0 = *(const short8*)&KV[wc * 16 + fr][fq * 8];
    short8 b1 = *(const short8*)&KV[wc * 16 + fr][32 + fq * 8];
    o0 = __builtin_amdgcn_mfma_f32_16x16x32_bf16(a0, b0, o0, 0, 0, 0);
    o0 = __builtin_amdgcn_mfma_f32_16x16x32_bf16(a1, b1, o0, 0, 0, 0);
    __syncthreads();
  }

  {
    const int d = h * DHH + wc * 16 + fr;
#pragma unroll
    for (int r = 0; r < 4; ++r) {
      const int row = i0 + wr * 16 + fq * 4 + r;
      AO[((size_t)b * SS + row) * DD + d] = f2bf(o0[r]);
    }
  }
}

// ---------------- residual + layernorm (fp32 out, optional bf16 shadow) ----------------
__global__ __launch_bounds__(256) void k_res_ln(
    const float* __restrict__ x, const float* __restrict__ r,
    const float* __restrict__ w, const float* __restrict__ b,
    float* __restrict__ out, unsigned short* __restrict__ outb) {
  __shared__ float red[4];
  const int row = blockIdx.x;
  const int tid = threadIdx.x;
  const int lane = tid & 63, wv = tid >> 6;
  float4 y = ((const float4*)(x + (size_t)row * DD))[tid];
  if (r) {
    float4 rr = ((const float4*)(r + (size_t)row * DD))[tid];
    y.x += rr.x; y.y += rr.y; y.z += rr.z; y.w += rr.w;
  }
  float s = y.x + y.y + y.z + y.w;
  s = wave_sum(s);
  if (lane == 0) red[wv] = s;
  __syncthreads();
  float mean = (red[0] + red[1] + red[2] + red[3]) * (1.0f / DD);
  __syncthreads();
  float d0 = y.x - mean, d1 = y.y - mean, d2 = y.z - mean, d3 = y.w - mean;
  float s2 = d0 * d0 + d1 * d1 + d2 * d2 + d3 * d3;
  s2 = wave_sum(s2);
  if (lane == 0) red[wv] = s2;
  __syncthreads();
  float var = (red[0] + red[1] + red[2] + red[3]) * (1.0f / DD);
  float rstd = rsqrtf(var + 1e-5f);
  float4 ww = ((const float4*)w)[tid];
  float4 bb = ((const float4*)b)[tid];
  float4 o;
  o.x = d0 * rstd * ww.x + bb.x;
  o.y = d1 * rstd * ww.y + bb.y;
  o.z = d2 * rstd * ww.z + bb.z;
  o.w = d3 * rstd * ww.w + bb.w;
  ((float4*)(out + (size_t)row * DD))[tid] = o;
  if (outb) {
    uint2 pk;
    pk.x = (unsigned)f2bf(o.x) | ((unsigned)f2bf(o.y) << 16);
    pk.y = (unsigned)f2bf(o.z) | ((unsigned)f2bf(o.w) << 16);
    *(uint2*)(outb + (size_t)row * DD + tid * 4) = pk;
  }
}

extern "C" void kernel_launch(void* const* d_in, const int* in_sizes, int n_in,
                              void* d_out, int out_size, void* d_ws, size_t ws_size,
                              hipStream_t stream) {
  (void)in_sizes; (void)n_in; (void)out_size; (void)ws_size;
  const float* x = (const float*)d_in[0];
  const float* Wq = (const float*)d_in[2];
  const float* bq = (const float*)d_in[3];
  const float* Wv = (const float*)d_in[4];
  const float* bv = (const float*)d_in[5];
  const float* Wo = (const float*)d_in[6];
  const float* bo = (const float*)d_in[7];
  const float* gam = (const float*)d_in[8];
  const float* lnw = (const float*)d_in[9];
  const float* lnb = (const float*)d_in[10];
  const float* flnw = (const float*)d_in[11];
  const float* flnb = (const float*)d_in[12];

  float* out0 = (float*)d_out;
  float* scores = out0 + (size_t)BB * SS * DD;
  const size_t BUF = (size_t)BB * SS * DD;       // 8.4M elems
  const size_t WSZ = (size_t)LL * DD * DD;       // 4.2M elems per weight set
  const size_t BHSS = (size_t)BB * HH * SS * SS; // 67.1M floats (scores)

  float* P0 = (float*)d_ws;
  float* P1 = P0 + BUF;
  unsigned short* us = (unsigned short*)(P1 + BUF);
  unsigned short* Abf = us;
  unsigned short* Qbf = us + BUF;
  unsigned short* VtB = us + 2 * BUF;
  unsigned short* AObf = us + 3 * BUF;
  unsigned short* Wob = us + 4 * BUF;            // ws total ~142.6 MB
  // Wq/Wv bf16 live at the tail of the scores region of d_out: their last
  // use (layer-3 q/v GEMMs) precedes the layer-3 attention that overwrites
  // the whole scores region with the real output.
  unsigned short* Wqb = (unsigned short*)scores + (2 * BHSS - 2 * WSZ);
  unsigned short* Wvb = Wqb + WSZ;

  const int M = BB * SS;  // 8192

  k_w2bf<<<dim3(WSZ / 1024), 256, 0, stream>>>(Wq, Wqb);
  k_w2bf<<<dim3(WSZ / 1024), 256, 0, stream>>>(Wv, Wvb);
  k_w2bf<<<dim3(WSZ / 1024), 256, 0, stream>>>(Wo, Wob);
  k_add_pe<<<dim3(BUF / 1024), 256, 0, stream>>>(x, P0, Abf);

  float* Acur = P0;
  float* Pnx = P1;
  for (int l = 0; l < LL; ++l) {
    k_gemm<0><<<dim3(512), 256, 0, stream>>>(Abf, Wqb + (size_t)l * DD * DD, bq + l * DD, Qbf);
    k_gemm<1><<<dim3(512), 256, 0, stream>>>(Abf, Wvb + (size_t)l * DD * DD, bv + l * DD, VtB);
    k_attn_mfma<<<dim3(BB * HH * (SS / 32)), 512, 0, stream>>>(
        Qbf, VtB, gam + l * HH, AObf, (l == LL - 1) ? scores : nullptr);
    k_gemm<2><<<dim3(512), 256, 0, stream>>>(AObf, Wob + (size_t)l * DD * DD, bo + l * DD, Pnx);
    k_res_ln<<<dim3(M), 256, 0, stream>>>(Acur, Pnx, lnw + l * DD, lnb + l * DD, Pnx, Abf);
    float* t = Acur; Acur = Pnx; Pnx = t;
  }
  k_res_ln<<<dim3(M), 256, 0, stream>>>(Acur, nullptr, flnw, flnb, out0, nullptr);
}

// Round 7
// 996.184 us; speedup vs baseline: 1.4193x; 1.2418x over previous
//
#include <hip/hip_runtime.h>
#include <hip/hip_bf16.h>

#define BB 16
#define SS 512
#define DD 1024
#define HH 16
#define LL 4
#define DHH 64
#define GK 1024
#define GN 1024

typedef __attribute__((ext_vector_type(8))) short short8;
typedef __attribute__((ext_vector_type(4))) float f32x4;

__device__ __forceinline__ unsigned short f2bf(float f) {
  union { float f; unsigned int u; } v; v.f = f;
  unsigned int r = v.u + 0x7FFFu + ((v.u >> 16) & 1u);
  return (unsigned short)(r >> 16);
}

__device__ __forceinline__ float wave_max(float v) {
#pragma unroll
  for (int off = 32; off > 0; off >>= 1) v = fmaxf(v, __shfl_xor(v, off));
  return v;
}
__device__ __forceinline__ float wave_sum(float v) {
#pragma unroll
  for (int off = 32; off > 0; off >>= 1) v += __shfl_xor(v, off);
  return v;
}
__device__ __forceinline__ float half_max(float v) {   // width-32 segment
#pragma unroll
  for (int off = 16; off > 0; off >>= 1) v = fmaxf(v, __shfl_xor(v, off));
  return v;
}
__device__ __forceinline__ float half_sum(float v) {
#pragma unroll
  for (int off = 16; off > 0; off >>= 1) v += __shfl_xor(v, off);
  return v;
}

// global -> LDS direct 16B copy (CK-style addrspace reinterpret).
// LDS dest is wave-uniform base + lane*16 (per-lane dest bits ignored).
__device__ __forceinline__ void gl16(const void* g, void* l) {
  __builtin_amdgcn_global_load_lds(
      (const __attribute__((address_space(1))) unsigned int*)(uintptr_t)g,
      (__attribute__((address_space(3))) unsigned int*)(unsigned int)(uintptr_t)l,
      16, 0, 0);
}

// ---------------- weights fp32 -> bf16 ----------------
__global__ __launch_bounds__(256) void k_w2bf(const float* __restrict__ w,
                                              unsigned short* __restrict__ o) {
  size_t i4 = ((size_t)blockIdx.x * 256 + threadIdx.x) * 4;
  float4 v = *(const float4*)(w + i4);
  uint2 pk;
  pk.x = (unsigned)f2bf(v.x) | ((unsigned)f2bf(v.y) << 16);
  pk.y = (unsigned)f2bf(v.z) | ((unsigned)f2bf(v.w) << 16);
  *(uint2*)(o + i4) = pk;
}

// ---------------- q0 = x + positional encoding (fp32 + bf16 shadow) ----------------
__global__ __launch_bounds__(256) void k_add_pe(const float* __restrict__ x,
                                                float* __restrict__ out,
                                                unsigned short* __restrict__ outb) {
  size_t i4 = ((size_t)blockIdx.x * 256 + threadIdx.x) * 4;
  int d0 = (int)(i4 & (DD - 1));
  int s = (int)((i4 >> 10) & (SS - 1));
  float4 xv = *(const float4*)(x + i4);
  int ip0 = d0 >> 1;
  float f0 = __expf((float)ip0 * -0.017988946039016f);
  float f1 = __expf((float)(ip0 + 1) * -0.017988946039016f);
  float s0v, c0v, s1v, c1v;
  __sincosf((float)s * f0, &s0v, &c0v);
  __sincosf((float)s * f1, &s1v, &c1v);
  float4 o;
  o.x = xv.x + s0v; o.y = xv.y + c0v; o.z = xv.z + s1v; o.w = xv.w + c1v;
  *(float4*)(out + i4) = o;
  uint2 pk;
  pk.x = (unsigned)f2bf(o.x) | ((unsigned)f2bf(o.y) << 16);
  pk.y = (unsigned)f2bf(o.z) | ((unsigned)f2bf(o.w) << 16);
  *(uint2*)(outb + i4) = pk;
}

// ---------------- C = A[M,K]bf16 @ W[N,K]^T bf16 + bias ----------------
// m97 structure: 128x128 tile, 4 waves (2x2), BK=32, global_load_lds 16B.
// MODE 0: bf16 [M,N] out.  MODE 1: bf16 transposed [b, col, s] out.  MODE 2: fp32 [M,N].
template <int MODE>
__global__ __launch_bounds__(256) void k_gemm(
    const unsigned short* __restrict__ A, const unsigned short* __restrict__ W,
    const float* __restrict__ bias, void* __restrict__ out) {
  __shared__ unsigned short As[128 * 32];
  __shared__ unsigned short Bs[128 * 32];
  const int tid = threadIdx.x;
  const int lane = tid & 63;
  const int w = tid >> 6;
  const int wr = w >> 1, wc = w & 1;
  const int fr = lane & 15, fq = lane >> 4;

  // XCD swizzle: 512 wgs = 8 XCDs x 64; each XCD owns one N-panel sweep
  int bid = blockIdx.x;
  bid = (bid & 7) * 64 + (bid >> 3);
  const int bm = (bid & 63) * 128;
  const int bn = (bid >> 6) * 128;

  f32x4 acc[4][4] = {};

  const unsigned short* ga = A + (size_t)(bm + w * 16 + (lane >> 2)) * GK + (lane & 3) * 8;
  const unsigned short* gb = W + (size_t)(bn + w * 16 + (lane >> 2)) * GK + (lane & 3) * 8;
  unsigned short* la = As + w * 512;   // wave-uniform LDS base
  unsigned short* lb = Bs + w * 512;

  for (int k0 = 0; k0 < GK; k0 += 32) {
    gl16(ga + k0, la);
    gl16(ga + 64 * GK + k0, la + 2048);
    gl16(gb + k0, lb);
    gl16(gb + 64 * GK + k0, lb + 2048);
    __syncthreads();
    short8 af[4], bf[4];
#pragma unroll
    for (int m = 0; m < 4; ++m)
      af[m] = *(const short8*)(As + (wr * 64 + m * 16 + fr) * 32 + fq * 8);
#pragma unroll
    for (int n = 0; n < 4; ++n)
      bf[n] = *(const short8*)(Bs + (wc * 64 + n * 16 + fr) * 32 + fq * 8);
#pragma unroll
    for (int m = 0; m < 4; ++m)
#pragma unroll
      for (int n = 0; n < 4; ++n)
        acc[m][n] = __builtin_amdgcn_mfma_f32_16x16x32_bf16(af[m], bf[n], acc[m][n], 0, 0, 0);
    __syncthreads();
  }

#pragma unroll
  for (int m = 0; m < 4; ++m) {
    const int row0 = bm + wr * 64 + m * 16 + fq * 4;
#pragma unroll
    for (int n = 0; n < 4; ++n) {
      const int col = bn + wc * 64 + n * 16 + fr;
      const float bsv = bias[col];
      if constexpr (MODE == 0) {
        unsigned short* o = (unsigned short*)out;
#pragma unroll
        for (int r = 0; r < 4; ++r)
          o[(size_t)(row0 + r) * GN + col] = f2bf(acc[m][n][r] + bsv);
      } else if constexpr (MODE == 1) {
        unsigned short* o = (unsigned short*)out;
        const int bi = row0 >> 9, si = row0 & (SS - 1);
        uint2 pk;
        pk.x = (unsigned)f2bf(acc[m][n][0] + bsv) | ((unsigned)f2bf(acc[m][n][1] + bsv) << 16);
        pk.y = (unsigned)f2bf(acc[m][n][2] + bsv) | ((unsigned)f2bf(acc[m][n][3] + bsv) << 16);
        *(uint2*)(o + ((size_t)bi * DD + col) * SS + si) = pk;
      } else {
        float* o = (float*)out;
#pragma unroll
        for (int r = 0; r < 4; ++r)
          o[(size_t)(row0 + r) * GN + col] = acc[m][n][r] + bsv;
      }
    }
  }
}

// ---------------- fused MFMA attention, BIG half (itiles 8..15) ----------------
// Round-4 structure verbatim: 32-row i-tile, 8 waves, full-width softmax
// (lane owns fixed jb=lane*8, float4 reads, one 6-step scan). 78 KB -> 2 blk/CU.
__global__ __launch_bounds__(512) void k_attn_big(
    const unsigned short* __restrict__ Q, const unsigned short* __restrict__ Vt,
    const float* __restrict__ gam, unsigned short* __restrict__ AO,
    float* __restrict__ scores_out) {
  __shared__ float sc_s[32][516];          // 66048 B
  __shared__ unsigned short Qs[32][72];    //  4608 B
  __shared__ unsigned short KV[64][72];    //  9216 B

  const int tid = threadIdx.x;
  const int lane = tid & 63;
  const int w = tid >> 6;
  const int wr = w & 1;
  const int wc = w >> 1;
  const int fr = lane & 15, fq = lane >> 4;

  const int itile = 8 + (blockIdx.x & 7);
  const int bh = blockIdx.x >> 3;
  const int b = bh >> 4;
  const int h = bh & 15;
  const int i0 = itile * 32;
  const int njt = (itile + 2) >> 1;        // 5..8
  const int jcap = njt * 64;

  const unsigned short* Qb = Q + (size_t)b * SS * DD + h * DHH;
  const unsigned short* Vtb = Vt + ((size_t)b * DD + h * DHH) * SS;
  const float gneg = -fabsf(gam[h]);

  const int srow = tid >> 3;
  const int sdb = (tid & 7) * 8;

  if (tid < 256) {
    const int qr = tid >> 3, qc = (tid & 7) * 8;
    *(short8*)&Qs[qr][qc] = *(const short8*)(Qb + (size_t)(i0 + qr) * DD + qc);
  }

  for (int jt = 0; jt < njt; ++jt) {
    *(short8*)&KV[srow][sdb] = *(const short8*)(Qb + (size_t)(jt * 64 + srow) * DD + sdb);
    __syncthreads();

    short8 a0 = *(const short8*)&Qs[wr * 16 + fr][fq * 8];
    short8 a1 = *(const short8*)&Qs[wr * 16 + fr][32 + fq * 8];
    short8 b0 = *(const short8*)&KV[wc * 16 + fr][fq * 8];
    short8 b1 = *(const short8*)&KV[wc * 16 + fr][32 + fq * 8];
    f32x4 s0 = {};
    s0 = __builtin_amdgcn_mfma_f32_16x16x32_bf16(a0, b0, s0, 0, 0, 0);
    s0 = __builtin_amdgcn_mfma_f32_16x16x32_bf16(a1, b1, s0, 0, 0, 0);

    const int j = jt * 64 + wc * 16 + fr;
#pragma unroll
    for (int r = 0; r < 4; ++r) {
      const int row = wr * 16 + fq * 4 + r;
      sc_s[row][j] = (j < i0 + row) ? s0[r] * 0.125f : -1e30f;
    }
    __syncthreads();
  }

  const int jb = lane << 3;
  for (int q = 0; q < 4; ++q) {
    const int r_i = w * 4 + q;
    const int gi = i0 + r_i;
    const float* rowp = &sc_s[r_i][0];
    float4 v0 = *(const float4*)(rowp + jb);
    float4 v1 = *(const float4*)(rowp + jb + 4);
    float sc[8] = {v0.x, v0.y, v0.z, v0.w, v1.x, v1.y, v1.z, v1.w};
#pragma unroll
    for (int c = 0; c < 8; ++c)
      if (jb + c >= jcap) sc[c] = -1e30f;

    float m1 = sc[0];
#pragma unroll
    for (int c = 1; c < 8; ++c) m1 = fmaxf(m1, sc[c]);
    m1 = wave_max(m1);
    float p[8];
    float lsum = 0.0f;
#pragma unroll
    for (int c = 0; c < 8; ++c) {
      p[c] = __expf(sc[c] - m1);
      lsum += p[c];
    }
    float tot = wave_sum(lsum);
    float inv = 1.0f / tot;

    float xs = lsum;
#pragma unroll
    for (int off = 1; off < 64; off <<= 1) {
      float y = __shfl_up(xs, off);
      if (lane >= off) xs += y;
    }
    float run = xs - lsum;

    float s2[8];
#pragma unroll
    for (int c = 0; c < 8; ++c) {
      run += p[c];
      float cum = run * inv;
      float dist = sqrtf(fmaxf((1.0f - cum) * (float)(gi - (jb + c)), 0.0f));
      float te = __expf(gneg * dist);
      te = fminf(fmaxf(te, 1e-5f), 1e5f);
      s2[c] = sc[c] * te;
    }

    float m2 = s2[0];
#pragma unroll
    for (int c = 1; c < 8; ++c) m2 = fmaxf(m2, s2[c]);
    m2 = wave_max(m2);
    float e[8];
    float lsum2 = 0.0f;
#pragma unroll
    for (int c = 0; c < 8; ++c) {
      e[c] = __expf(s2[c] - m2);
      lsum2 += e[c];
    }
    float tot2 = wave_sum(lsum2);
    float mult = fminf(tot2, 5.0f) / tot2;

    float av[8];
#pragma unroll
    for (int c = 0; c < 8; ++c) {
      av[c] = (gi == 0) ? 0.0f : e[c] * mult;
    }

    if (scores_out) {
      float* so = scores_out + ((size_t)(b * HH + h) * SS + gi) * SS + jb;
      *(float4*)(so) = make_float4(av[0], av[1], av[2], av[3]);
      *(float4*)(so + 4) = make_float4(av[4], av[5], av[6], av[7]);
    }

    short8 pk;
#pragma unroll
    for (int c = 0; c < 8; ++c) pk[c] = (short)f2bf(av[c]);
    *(short8*)((unsigned short*)&sc_s[r_i][0] + jb) = pk;
  }
  __syncthreads();

  f32x4 o0 = {};
  for (int jt = 0; jt < njt; ++jt) {
    *(short8*)&KV[srow][sdb] =
        *(const short8*)(Vtb + (size_t)srow * SS + jt * 64 + sdb);
    __syncthreads();

    const unsigned short* arow = (const unsigned short*)&sc_s[wr * 16 + fr][0];
    short8 a0 = *(const short8*)(arow + jt * 64 + fq * 8);
    short8 a1 = *(const short8*)(arow + jt * 64 + 32 + fq * 8);
    short8 b0 = *(const short8*)&KV[wc * 16 + fr][fq * 8];
    short8 b1 = *(const short8*)&KV[wc * 16 + fr][32 + fq * 8];
    o0 = __builtin_amdgcn_mfma_f32_16x16x32_bf16(a0, b0, o0, 0, 0, 0);
    o0 = __builtin_amdgcn_mfma_f32_16x16x32_bf16(a1, b1, o0, 0, 0, 0);
    __syncthreads();
  }

  {
    const int d = h * DHH + wc * 16 + fr;
#pragma unroll
    for (int r = 0; r < 4; ++r) {
      const int row = i0 + wr * 16 + fq * 4 + r;
      AO[((size_t)b * SS + row) * DD + d] = f2bf(o0[r]);
    }
  }
}

// ---------------- fused MFMA attention, SMALL half (itiles 0..7) ----------------
// jcap <= 256, so each wave processes TWO rows per pass (lane halves,
// width-32 segmented max/sum/scan) -- same vectorized access shape as big,
// half the softmax passes. sc_s[32][260] -> LDS 46 KB -> 3 blocks/CU.
__global__ __launch_bounds__(512) void k_attn_small(
    const unsigned short* __restrict__ Q, const unsigned short* __restrict__ Vt,
    const float* __restrict__ gam, unsigned short* __restrict__ AO,
    float* __restrict__ scores_out) {
  __shared__ float sc_s[32][260];          // 33280 B
  __shared__ unsigned short Qs[32][72];    //  4608 B
  __shared__ unsigned short KV[64][72];    //  9216 B  => 47104 B total

  const int tid = threadIdx.x;
  const int lane = tid & 63;
  const int w = tid >> 6;
  const int wr = w & 1;
  const int wc = w >> 1;
  const int fr = lane & 15, fq = lane >> 4;

  const int itile = blockIdx.x & 7;        // 0..7
  const int bh = blockIdx.x >> 3;
  const int b = bh >> 4;
  const int h = bh & 15;
  const int i0 = itile * 32;
  const int njt = (itile + 2) >> 1;        // 1..4
  const int jcap = njt * 64;

  const unsigned short* Qb = Q + (size_t)b * SS * DD + h * DHH;
  const unsigned short* Vtb = Vt + ((size_t)b * DD + h * DHH) * SS;
  const float gneg = -fabsf(gam[h]);

  const int srow = tid >> 3;
  const int sdb = (tid & 7) * 8;

  if (tid < 256) {
    const int qr = tid >> 3, qc = (tid & 7) * 8;
    *(short8*)&Qs[qr][qc] = *(const short8*)(Qb + (size_t)(i0 + qr) * DD + qc);
  }

  for (int jt = 0; jt < njt; ++jt) {
    *(short8*)&KV[srow][sdb] = *(const short8*)(Qb + (size_t)(jt * 64 + srow) * DD + sdb);
    __syncthreads();

    short8 a0 = *(const short8*)&Qs[wr * 16 + fr][fq * 8];
    short8 a1 = *(const short8*)&Qs[wr * 16 + fr][32 + fq * 8];
    short8 b0 = *(const short8*)&KV[wc * 16 + fr][fq * 8];
    short8 b1 = *(const short8*)&KV[wc * 16 + fr][32 + fq * 8];
    f32x4 s0 = {};
    s0 = __builtin_amdgcn_mfma_f32_16x16x32_bf16(a0, b0, s0, 0, 0, 0);
    s0 = __builtin_amdgcn_mfma_f32_16x16x32_bf16(a1, b1, s0, 0, 0, 0);

    const int j = jt * 64 + wc * 16 + fr;
#pragma unroll
    for (int r = 0; r < 4; ++r) {
      const int row = wr * 16 + fq * 4 + r;
      sc_s[row][j] = (j < i0 + row) ? s0[r] * 0.125f : -1e30f;
    }
    __syncthreads();
  }

  // two rows per pass: half = lane>>5 selects row, ll = lane&31 owns j=ll*8..+7
  const int half = lane >> 5;
  const int ll = lane & 31;
  const int jb = ll << 3;
  for (int q = 0; q < 2; ++q) {
    const int r_i = w * 4 + q * 2 + half;
    const int gi = i0 + r_i;
    const float* rowp = &sc_s[r_i][0];
    float4 v0 = *(const float4*)(rowp + jb);
    float4 v1 = *(const float4*)(rowp + jb + 4);
    float sc[8] = {v0.x, v0.y, v0.z, v0.w, v1.x, v1.y, v1.z, v1.w};
#pragma unroll
    for (int c = 0; c < 8; ++c)
      if (jb + c >= jcap) sc[c] = -1e30f;

    float m1 = sc[0];
#pragma unroll
    for (int c = 1; c < 8; ++c) m1 = fmaxf(m1, sc[c]);
    m1 = half_max(m1);
    float p[8];
    float lsum = 0.0f;
#pragma unroll
    for (int c = 0; c < 8; ++c) {
      p[c] = __expf(sc[c] - m1);
      lsum += p[c];
    }

    float xs = lsum;
#pragma unroll
    for (int off = 1; off < 32; off <<= 1) {
      float y = __shfl_up(xs, off, 32);
      if (ll >= off) xs += y;
    }
    const float tot = __shfl(xs, 31, 32);   // segment total
    const float inv = 1.0f / tot;
    float run = xs - lsum;

    float s2[8];
#pragma unroll
    for (int c = 0; c < 8; ++c) {
      run += p[c];
      float cum = run * inv;
      float dist = sqrtf(fmaxf((1.0f - cum) * (float)(gi - (jb + c)), 0.0f));
      float te = __expf(gneg * dist);
      te = fminf(fmaxf(te, 1e-5f), 1e5f);
      s2[c] = sc[c] * te;
    }

    float m2 = s2[0];
#pragma unroll
    for (int c = 1; c < 8; ++c) m2 = fmaxf(m2, s2[c]);
    m2 = half_max(m2);
    float e[8];
    float lsum2 = 0.0f;
#pragma unroll
    for (int c = 0; c < 8; ++c) {
      e[c] = __expf(s2[c] - m2);
      lsum2 += e[c];
    }
    const float tot2 = half_sum(lsum2);
    const float mult = fminf(tot2, 5.0f) / tot2;

    float av[8];
#pragma unroll
    for (int c = 0; c < 8; ++c) {
      av[c] = (gi == 0) ? 0.0f : e[c] * mult;
    }

    if (scores_out) {
      float* so = scores_out + ((size_t)(b * HH + h) * SS + gi) * SS + jb;
      *(float4*)(so) = make_float4(av[0], av[1], av[2], av[3]);
      *(float4*)(so + 4) = make_float4(av[4], av[5], av[6], av[7]);
      // zero tail [256,512)
      *(float4*)(so + 256) = make_float4(0.f, 0.f, 0.f, 0.f);
      *(float4*)(so + 260) = make_float4(0.f, 0.f, 0.f, 0.f);
    }

    short8 pk;
#pragma unroll
    for (int c = 0; c < 8; ++c) pk[c] = (short)f2bf(av[c]);
    *(short8*)((unsigned short*)&sc_s[r_i][0] + jb) = pk;
  }
  __syncthreads();

  f32x4 o0 = {};
  for (int jt = 0; jt < njt; ++jt) {
    *(short8*)&KV[srow][sdb] =
        *(const short8*)(Vtb + (size_t)srow * SS + jt * 64 + sdb);
    __syncthreads();

    const unsigned short* arow = (const unsigned short*)&sc_s[wr * 16 + fr][0];
    short8 a0 = *(const short8*)(arow + jt * 64 + fq * 8);
    short8 a1 = *(const short8*)(arow + jt * 64 + 32 + fq * 8);
    short8 b0 = *(const short8*)&KV[wc * 16 + fr][fq * 8];
    short8 b1 = *(const short8*)&KV[wc * 16 + fr][32 + fq * 8];
    o0 = __builtin_amdgcn_mfma_f32_16x16x32_bf16(a0, b0, o0, 0, 0, 0);
    o0 = __builtin_amdgcn_mfma_f32_16x16x32_bf16(a1, b1, o0, 0, 0, 0);
    __syncthreads();
  }

  {
    const int d = h * DHH + wc * 16 + fr;
#pragma unroll
    for (int r = 0; r < 4; ++r) {
      const int row = i0 + wr * 16 + fq * 4 + r;
      AO[((size_t)b * SS + row) * DD + d] = f2bf(o0[r]);
    }
  }
}

// ---------------- residual + layernorm (fp32 out, optional bf16 shadow) ----------------
__global__ __launch_bounds__(256) void k_res_ln(
    const float* __restrict__ x, const float* __restrict__ r,
    const float* __restrict__ w, const float* __restrict__ b,
    float* __restrict__ out, unsigned short* __restrict__ outb) {
  __shared__ float red[4];
  const int row = blockIdx.x;
  const int tid = threadIdx.x;
  const int lane = tid & 63, wv = tid >> 6;
  float4 y = ((const float4*)(x + (size_t)row * DD))[tid];
  if (r) {
    float4 rr = ((const float4*)(r + (size_t)row * DD))[tid];
    y.x += rr.x; y.y += rr.y; y.z += rr.z; y.w += rr.w;
  }
  float s = y.x + y.y + y.z + y.w;
  s = wave_sum(s);
  if (lane == 0) red[wv] = s;
  __syncthreads();
  float mean = (red[0] + red[1] + red[2] + red[3]) * (1.0f / DD);
  __syncthreads();
  float d0 = y.x - mean, d1 = y.y - mean, d2 = y.z - mean, d3 = y.w - mean;
  float s2 = d0 * d0 + d1 * d1 + d2 * d2 + d3 * d3;
  s2 = wave_sum(s2);
  if (lane == 0) red[wv] = s2;
  __syncthreads();
  float var = (red[0] + red[1] + red[2] + red[3]) * (1.0f / DD);
  float rstd = rsqrtf(var + 1e-5f);
  float4 ww = ((const float4*)w)[tid];
  float4 bb = ((const float4*)b)[tid];
  float4 o;
  o.x = d0 * rstd * ww.x + bb.x;
  o.y = d1 * rstd * ww.y + bb.y;
  o.z = d2 * rstd * ww.z + bb.z;
  o.w = d3 * rstd * ww.w + bb.w;
  ((float4*)(out + (size_t)row * DD))[tid] = o;
  if (outb) {
    uint2 pk;
    pk.x = (unsigned)f2bf(o.x) | ((unsigned)f2bf(o.y) << 16);
    pk.y = (unsigned)f2bf(o.z) | ((unsigned)f2bf(o.w) << 16);
    *(uint2*)(outb + (size_t)row * DD + tid * 4) = pk;
  }
}

extern "C" void kernel_launch(void* const* d_in, const int* in_sizes, int n_in,
                              void* d_out, int out_size, void* d_ws, size_t ws_size,
                              hipStream_t stream) {
  (void)in_sizes; (void)n_in; (void)out_size; (void)ws_size;
  const float* x = (const float*)d_in[0];
  const float* Wq = (const float*)d_in[2];
  const float* bq = (const float*)d_in[3];
  const float* Wv = (const float*)d_in[4];
  const float* bv = (const float*)d_in[5];
  const float* Wo = (const float*)d_in[6];
  const float* bo = (const float*)d_in[7];
  const float* gam = (const float*)d_in[8];
  const float* lnw = (const float*)d_in[9];
  const float* lnb = (const float*)d_in[10];
  const float* flnw = (const float*)d_in[11];
  const float* flnb = (const float*)d_in[12];

  float* out0 = (float*)d_out;
  float* scores = out0 + (size_t)BB * SS * DD;
  const size_t BUF = (size_t)BB * SS * DD;       // 8.4M elems
  const size_t WSZ = (size_t)LL * DD * DD;       // 4.2M elems per weight set
  const size_t BHSS = (size_t)BB * HH * SS * SS; // 67.1M floats (scores)

  float* P0 = (float*)d_ws;
  float* P1 = P0 + BUF;
  unsigned short* us = (unsigned short*)(P1 + BUF);
  unsigned short* Abf = us;
  unsigned short* Qbf = us + BUF;
  unsigned short* VtB = us + 2 * BUF;
  unsigned short* AObf = us + 3 * BUF;
  unsigned short* Wob = us + 4 * BUF;            // ws total ~142.6 MB
  // Wq/Wv bf16 live at the tail of the scores region of d_out: their last
  // use (layer-3 q/v GEMMs) precedes the layer-3 attention that overwrites
  // the whole scores region with the real output.
  unsigned short* Wqb = (unsigned short*)scores + (2 * BHSS - 2 * WSZ);
  unsigned short* Wvb = Wqb + WSZ;

  const int M = BB * SS;  // 8192

  k_w2bf<<<dim3(WSZ / 1024), 256, 0, stream>>>(Wq, Wqb);
  k_w2bf<<<dim3(WSZ / 1024), 256, 0, stream>>>(Wv, Wvb);
  k_w2bf<<<dim3(WSZ / 1024), 256, 0, stream>>>(Wo, Wob);
  k_add_pe<<<dim3(BUF / 1024), 256, 0, stream>>>(x, P0, Abf);

  float* Acur = P0;
  float* Pnx = P1;
  for (int l = 0; l < LL; ++l) {
    float* sc_dst = (l == LL - 1) ? scores : nullptr;
    k_gemm<0><<<dim3(512), 256, 0, stream>>>(Abf, Wqb + (size_t)l * DD * DD, bq + l * DD, Qbf);
    k_gemm<1><<<dim3(512), 256, 0, stream>>>(Abf, Wvb + (size_t)l * DD * DD, bv + l * DD, VtB);
    k_attn_small<<<dim3(BB * HH * 8), 512, 0, stream>>>(Qbf, VtB, gam + l * HH, AObf, sc_dst);
    k_attn_big<<<dim3(BB * HH * 8), 512, 0, stream>>>(Qbf, VtB, gam + l * HH, AObf, sc_dst);
    k_gemm<2><<<dim3(512), 256, 0, stream>>>(AObf, Wob + (size_t)l * DD * DD, bo + l * DD, Pnx);
    k_res_ln<<<dim3(M), 256, 0, stream>>>(Acur, Pnx, lnw + l * DD, lnb + l * DD, Pnx, Abf);
    float* t = Acur; Acur = Pnx; Pnx = t;
  }
  k_res_ln<<<dim3(M), 256, 0, stream>>>(Acur, nullptr, flnw, flnb, out0, nullptr);
}

// Round 8
// 943.174 us; speedup vs baseline: 1.4990x; 1.0562x over previous
//
#include <hip/hip_runtime.h>
#include <hip/hip_bf16.h>

#define BB 16
#define SS 512
#define DD 1024
#define HH 16
#define LL 4
#define DHH 64
#define GK 1024

typedef __attribute__((ext_vector_type(8))) short short8;
typedef __attribute__((ext_vector_type(4))) float f32x4;

__device__ __forceinline__ unsigned short f2bf(float f) {
  union { float f; unsigned int u; } v; v.f = f;
  unsigned int r = v.u + 0x7FFFu + ((v.u >> 16) & 1u);
  return (unsigned short)(r >> 16);
}

__device__ __forceinline__ float wave_max(float v) {
#pragma unroll
  for (int off = 32; off > 0; off >>= 1) v = fmaxf(v, __shfl_xor(v, off));
  return v;
}
__device__ __forceinline__ float wave_sum(float v) {
#pragma unroll
  for (int off = 32; off > 0; off >>= 1) v += __shfl_xor(v, off);
  return v;
}
__device__ __forceinline__ float half_max(float v) {   // width-32 segment
#pragma unroll
  for (int off = 16; off > 0; off >>= 1) v = fmaxf(v, __shfl_xor(v, off));
  return v;
}
__device__ __forceinline__ float half_sum(float v) {
#pragma unroll
  for (int off = 16; off > 0; off >>= 1) v += __shfl_xor(v, off);
  return v;
}

// global -> LDS direct 16B copy. LDS dest is wave-uniform base + lane*16.
__device__ __forceinline__ void gl16(const void* g, void* l) {
  __builtin_amdgcn_global_load_lds(
      (const __attribute__((address_space(1))) unsigned int*)(uintptr_t)g,
      (__attribute__((address_space(3))) unsigned int*)(unsigned int)(uintptr_t)l,
      16, 0, 0);
}

// ---------------- weights fp32 -> bf16 ----------------
// Wq/Wv interleaved per layer into [L][2048][1024] (rows 0-1023 = Wq, 1024-2047 = Wv)
__global__ __launch_bounds__(256) void k_w2bf_qv(const float* __restrict__ wq,
                                                 const float* __restrict__ wv,
                                                 unsigned short* __restrict__ o) {
  size_t i4 = ((size_t)blockIdx.x * 256 + threadIdx.x) * 4;   // dst index
  size_t l = i4 >> 21;                    // 2048*1024 elems per layer
  size_t r = i4 & ((1u << 21) - 1);
  const float* src = (r < (1u << 20)) ? wq + (l << 20) + r
                                      : wv + (l << 20) + (r - (1u << 20));
  float4 v = *(const float4*)src;
  uint2 pk;
  pk.x = (unsigned)f2bf(v.x) | ((unsigned)f2bf(v.y) << 16);
  pk.y = (unsigned)f2bf(v.z) | ((unsigned)f2bf(v.w) << 16);
  *(uint2*)(o + i4) = pk;
}
__global__ __launch_bounds__(256) void k_w2bf(const float* __restrict__ w,
                                              unsigned short* __restrict__ o) {
  size_t i4 = ((size_t)blockIdx.x * 256 + threadIdx.x) * 4;
  float4 v = *(const float4*)(w + i4);
  uint2 pk;
  pk.x = (unsigned)f2bf(v.x) | ((unsigned)f2bf(v.y) << 16);
  pk.y = (unsigned)f2bf(v.z) | ((unsigned)f2bf(v.w) << 16);
  *(uint2*)(o + i4) = pk;
}

// ---------------- q0 = x + positional encoding (fp32 + bf16 shadow) ----------------
__global__ __launch_bounds__(256) void k_add_pe(const float* __restrict__ x,
                                                float* __restrict__ out,
                                                unsigned short* __restrict__ outb) {
  size_t i4 = ((size_t)blockIdx.x * 256 + threadIdx.x) * 4;
  int d0 = (int)(i4 & (DD - 1));
  int s = (int)((i4 >> 10) & (SS - 1));
  float4 xv = *(const float4*)(x + i4);
  int ip0 = d0 >> 1;
  float f0 = __expf((float)ip0 * -0.017988946039016f);
  float f1 = __expf((float)(ip0 + 1) * -0.017988946039016f);
  float s0v, c0v, s1v, c1v;
  __sincosf((float)s * f0, &s0v, &c0v);
  __sincosf((float)s * f1, &s1v, &c1v);
  float4 o;
  o.x = xv.x + s0v; o.y = xv.y + c0v; o.z = xv.z + s1v; o.w = xv.w + c1v;
  *(float4*)(out + i4) = o;
  uint2 pk;
  pk.x = (unsigned)f2bf(o.x) | ((unsigned)f2bf(o.y) << 16);
  pk.y = (unsigned)f2bf(o.z) | ((unsigned)f2bf(o.w) << 16);
  *(uint2*)(outb + i4) = pk;
}

// ---------------- C = A[M,K]bf16 @ W[N,K]^T bf16 + bias ----------------
// 128x128 tile, 4 waves, BK=32, gl16 staging, 2-phase double-buffered LDS:
// STAGE(t+1) issued BEFORE MFMA(t), single barrier per K-step (T3-minimum).
// MODE 0: bf16 [M,1024] out. MODE 2: fp32 [M,1024] out.
// MODE 3: fused QV (N=2048): col<1024 -> bf16 Qbf; col>=1024 -> transposed VtB.
template <int MODE>
__global__ __launch_bounds__(256) void k_gemm(
    const unsigned short* __restrict__ A, const unsigned short* __restrict__ W,
    const float* __restrict__ bias, const float* __restrict__ bias2,
    void* __restrict__ out, void* __restrict__ out2) {
  __shared__ unsigned short As[2][128 * 32];
  __shared__ unsigned short Bs[2][128 * 32];
  const int tid = threadIdx.x;
  const int lane = tid & 63;
  const int w = tid >> 6;
  const int wr = w >> 1, wc = w & 1;
  const int fr = lane & 15, fq = lane >> 4;

  // XCD swizzle (nwg divisible by 8)
  int bid = blockIdx.x;
  const int cpx = gridDim.x >> 3;
  bid = (bid & 7) * cpx + (bid >> 3);
  const int bm = (bid & 63) * 128;
  const int bn = (bid >> 6) * 128;

  f32x4 acc[4][4] = {};

  const unsigned short* ga = A + (size_t)(bm + w * 16 + (lane >> 2)) * GK + (lane & 3) * 8;
  const unsigned short* gb = W + (size_t)(bn + w * 16 + (lane >> 2)) * GK + (lane & 3) * 8;

  auto STAGE = [&](int buf, int k0) {
    unsigned short* la = As[buf] + w * 512;
    unsigned short* lb = Bs[buf] + w * 512;
    gl16(ga + k0, la);
    gl16(ga + 64 * GK + k0, la + 2048);
    gl16(gb + k0, lb);
    gl16(gb + 64 * GK + k0, lb + 2048);
  };

  STAGE(0, 0);
  __syncthreads();
  int cur = 0;
  for (int k0 = 0; k0 < GK; k0 += 32) {
    if (k0 + 32 < GK) STAGE(cur ^ 1, k0 + 32);
    short8 af[4], bf[4];
#pragma unroll
    for (int m = 0; m < 4; ++m)
      af[m] = *(const short8*)(As[cur] + (wr * 64 + m * 16 + fr) * 32 + fq * 8);
#pragma unroll
    for (int n = 0; n < 4; ++n)
      bf[n] = *(const short8*)(Bs[cur] + (wc * 64 + n * 16 + fr) * 32 + fq * 8);
#pragma unroll
    for (int m = 0; m < 4; ++m)
#pragma unroll
      for (int n = 0; n < 4; ++n)
        acc[m][n] = __builtin_amdgcn_mfma_f32_16x16x32_bf16(af[m], bf[n], acc[m][n], 0, 0, 0);
    __syncthreads();   // drains vmcnt(0): next buffer ready; cur consumed
    cur ^= 1;
  }

#pragma unroll
  for (int m = 0; m < 4; ++m) {
    const int row0 = bm + wr * 64 + m * 16 + fq * 4;
#pragma unroll
    for (int n = 0; n < 4; ++n) {
      const int col = bn + wc * 64 + n * 16 + fr;
      if constexpr (MODE == 0) {
        const float bsv = bias[col];
        unsigned short* o = (unsigned short*)out;
#pragma unroll
        for (int r = 0; r < 4; ++r)
          o[(size_t)(row0 + r) * DD + col] = f2bf(acc[m][n][r] + bsv);
      } else if constexpr (MODE == 2) {
        const float bsv = bias[col];
        float* o = (float*)out;
#pragma unroll
        for (int r = 0; r < 4; ++r)
          o[(size_t)(row0 + r) * DD + col] = acc[m][n][r] + bsv;
      } else {  // MODE 3: fused QV
        if (col < DD) {
          const float bsv = bias[col];
          unsigned short* o = (unsigned short*)out;
#pragma unroll
          for (int r = 0; r < 4; ++r)
            o[(size_t)(row0 + r) * DD + col] = f2bf(acc[m][n][r] + bsv);
        } else {
          const int c2 = col - DD;
          const float bsv = bias2[c2];
          unsigned short* o = (unsigned short*)out2;
          const int bi = row0 >> 9, si = row0 & (SS - 1);
          uint2 pk;
          pk.x = (unsigned)f2bf(acc[m][n][0] + bsv) | ((unsigned)f2bf(acc[m][n][1] + bsv) << 16);
          pk.y = (unsigned)f2bf(acc[m][n][2] + bsv) | ((unsigned)f2bf(acc[m][n][3] + bsv) << 16);
          *(uint2*)(o + ((size_t)bi * DD + c2) * SS + si) = pk;
        }
      }
    }
  }
}

// ---------------- fused MFMA attention, BIG half (itiles 8..15) ----------------
// r7 structure + K/V register-prefetch one tile ahead (T14) + softmax unroll-2.
__global__ __launch_bounds__(512) void k_attn_big(
    const unsigned short* __restrict__ Q, const unsigned short* __restrict__ Vt,
    const float* __restrict__ gam, unsigned short* __restrict__ AO,
    float* __restrict__ scores_out) {
  __shared__ float sc_s[32][516];          // 66048 B
  __shared__ unsigned short Qs[32][72];    //  4608 B
  __shared__ unsigned short KV[64][72];    //  9216 B

  const int tid = threadIdx.x;
  const int lane = tid & 63;
  const int w = tid >> 6;
  const int wr = w & 1;
  const int wc = w >> 1;
  const int fr = lane & 15, fq = lane >> 4;

  const int itile = 8 + (blockIdx.x & 7);
  const int bh = blockIdx.x >> 3;
  const int b = bh >> 4;
  const int h = bh & 15;
  const int i0 = itile * 32;
  const int njt = (itile + 2) >> 1;        // 5..8
  const int jcap = njt * 64;

  const unsigned short* Qb = Q + (size_t)b * SS * DD + h * DHH;
  const unsigned short* Vtb = Vt + ((size_t)b * DD + h * DHH) * SS;
  const float gneg = -fabsf(gam[h]);

  const int srow = tid >> 3;
  const int sdb = (tid & 7) * 8;

  if (tid < 256) {
    const int qr = tid >> 3, qc = (tid & 7) * 8;
    *(short8*)&Qs[qr][qc] = *(const short8*)(Qb + (size_t)(i0 + qr) * DD + qc);
  }

  // K prefetch: tile 0
  short8 kreg = *(const short8*)(Qb + (size_t)srow * DD + sdb);
  for (int jt = 0; jt < njt; ++jt) {
    *(short8*)&KV[srow][sdb] = kreg;
    // prefetch next K tile, or V tile 0 on the last iteration
    const unsigned short* nsrc = (jt + 1 < njt)
        ? Qb + (size_t)((jt + 1) * 64 + srow) * DD + sdb
        : Vtb + (size_t)srow * SS + sdb;
    kreg = *(const short8*)nsrc;
    __syncthreads();

    short8 a0 = *(const short8*)&Qs[wr * 16 + fr][fq * 8];
    short8 a1 = *(const short8*)&Qs[wr * 16 + fr][32 + fq * 8];
    short8 b0 = *(const short8*)&KV[wc * 16 + fr][fq * 8];
    short8 b1 = *(const short8*)&KV[wc * 16 + fr][32 + fq * 8];
    f32x4 s0 = {};
    s0 = __builtin_amdgcn_mfma_f32_16x16x32_bf16(a0, b0, s0, 0, 0, 0);
    s0 = __builtin_amdgcn_mfma_f32_16x16x32_bf16(a1, b1, s0, 0, 0, 0);

    const int j = jt * 64 + wc * 16 + fr;
#pragma unroll
    for (int r = 0; r < 4; ++r) {
      const int row = wr * 16 + fq * 4 + r;
      sc_s[row][j] = (j < i0 + row) ? s0[r] * 0.125f : -1e30f;
    }
    __syncthreads();
  }
  // V tile 0 into KV (K reads all done at the loop's final barrier)
  *(short8*)&KV[srow][sdb] = kreg;

  const int jb = lane << 3;
#pragma unroll 2
  for (int q = 0; q < 4; ++q) {
    const int r_i = w * 4 + q;
    const int gi = i0 + r_i;
    const float* rowp = &sc_s[r_i][0];
    float4 v0 = *(const float4*)(rowp + jb);
    float4 v1 = *(const float4*)(rowp + jb + 4);
    float sc[8] = {v0.x, v0.y, v0.z, v0.w, v1.x, v1.y, v1.z, v1.w};
#pragma unroll
    for (int c = 0; c < 8; ++c)
      if (jb + c >= jcap) sc[c] = -1e30f;

    float m1 = sc[0];
#pragma unroll
    for (int c = 1; c < 8; ++c) m1 = fmaxf(m1, sc[c]);
    m1 = wave_max(m1);
    float p[8];
    float lsum = 0.0f;
#pragma unroll
    for (int c = 0; c < 8; ++c) {
      p[c] = __expf(sc[c] - m1);
      lsum += p[c];
    }
    float tot = wave_sum(lsum);
    float inv = 1.0f / tot;

    float xs = lsum;
#pragma unroll
    for (int off = 1; off < 64; off <<= 1) {
      float y = __shfl_up(xs, off);
      if (lane >= off) xs += y;
    }
    float run = xs - lsum;

    float s2[8];
#pragma unroll
    for (int c = 0; c < 8; ++c) {
      run += p[c];
      float cum = run * inv;
      float dist = sqrtf(fmaxf((1.0f - cum) * (float)(gi - (jb + c)), 0.0f));
      float te = __expf(gneg * dist);
      te = fminf(fmaxf(te, 1e-5f), 1e5f);
      s2[c] = sc[c] * te;
    }

    float m2 = s2[0];
#pragma unroll
    for (int c = 1; c < 8; ++c) m2 = fmaxf(m2, s2[c]);
    m2 = wave_max(m2);
    float e[8];
    float lsum2 = 0.0f;
#pragma unroll
    for (int c = 0; c < 8; ++c) {
      e[c] = __expf(s2[c] - m2);
      lsum2 += e[c];
    }
    float tot2 = wave_sum(lsum2);
    float mult = fminf(tot2, 5.0f) / tot2;

    float av[8];
#pragma unroll
    for (int c = 0; c < 8; ++c) {
      av[c] = (gi == 0) ? 0.0f : e[c] * mult;
    }

    if (scores_out) {
      float* so = scores_out + ((size_t)(b * HH + h) * SS + gi) * SS + jb;
      *(float4*)(so) = make_float4(av[0], av[1], av[2], av[3]);
      *(float4*)(so + 4) = make_float4(av[4], av[5], av[6], av[7]);
    }

    short8 pk;
#pragma unroll
    for (int c = 0; c < 8; ++c) pk[c] = (short)f2bf(av[c]);
    *(short8*)((unsigned short*)&sc_s[r_i][0] + jb) = pk;
  }
  __syncthreads();   // attn bf16 + V0 visible

  // PV with V register-prefetch one tile ahead
  short8 vreg;
  if (njt > 1) vreg = *(const short8*)(Vtb + (size_t)srow * SS + 64 + sdb);
  f32x4 o0 = {};
  for (int jt = 0; jt < njt; ++jt) {
    const unsigned short* arow = (const unsigned short*)&sc_s[wr * 16 + fr][0];
    short8 a0 = *(const short8*)(arow + jt * 64 + fq * 8);
    short8 a1 = *(const short8*)(arow + jt * 64 + 32 + fq * 8);
    short8 b0 = *(const short8*)&KV[wc * 16 + fr][fq * 8];
    short8 b1 = *(const short8*)&KV[wc * 16 + fr][32 + fq * 8];
    o0 = __builtin_amdgcn_mfma_f32_16x16x32_bf16(a0, b0, o0, 0, 0, 0);
    o0 = __builtin_amdgcn_mfma_f32_16x16x32_bf16(a1, b1, o0, 0, 0, 0);
    __syncthreads();                       // KV reads done
    if (jt + 1 < njt) {
      *(short8*)&KV[srow][sdb] = vreg;
      if (jt + 2 < njt) vreg = *(const short8*)(Vtb + (size_t)srow * SS + (jt + 2) * 64 + sdb);
      __syncthreads();                     // next V tile visible
    }
  }

  {
    const int d = h * DHH + wc * 16 + fr;
#pragma unroll
    for (int r = 0; r < 4; ++r) {
      const int row = i0 + wr * 16 + fq * 4 + r;
      AO[((size_t)b * SS + row) * DD + d] = f2bf(o0[r]);
    }
  }
}

// ---------------- fused MFMA attention, SMALL half (itiles 0..7) ----------------
// Two rows per softmax pass (width-32 segments) + K/V register prefetch.
__global__ __launch_bounds__(512) void k_attn_small(
    const unsigned short* __restrict__ Q, const unsigned short* __restrict__ Vt,
    const float* __restrict__ gam, unsigned short* __restrict__ AO,
    float* __restrict__ scores_out) {
  __shared__ float sc_s[32][260];          // 33280 B
  __shared__ unsigned short Qs[32][72];    //  4608 B
  __shared__ unsigned short KV[64][72];    //  9216 B => 47104 B

  const int tid = threadIdx.x;
  const int lane = tid & 63;
  const int w = tid >> 6;
  const int wr = w & 1;
  const int wc = w >> 1;
  const int fr = lane & 15, fq = lane >> 4;

  const int itile = blockIdx.x & 7;        // 0..7
  const int bh = blockIdx.x >> 3;
  const int b = bh >> 4;
  const int h = bh & 15;
  const int i0 = itile * 32;
  const int njt = (itile + 2) >> 1;        // 1..4
  const int jcap = njt * 64;

  const unsigned short* Qb = Q + (size_t)b * SS * DD + h * DHH;
  const unsigned short* Vtb = Vt + ((size_t)b * DD + h * DHH) * SS;
  const float gneg = -fabsf(gam[h]);

  const int srow = tid >> 3;
  const int sdb = (tid & 7) * 8;

  if (tid < 256) {
    const int qr = tid >> 3, qc = (tid & 7) * 8;
    *(short8*)&Qs[qr][qc] = *(const short8*)(Qb + (size_t)(i0 + qr) * DD + qc);
  }

  short8 kreg = *(const short8*)(Qb + (size_t)srow * DD + sdb);
  for (int jt = 0; jt < njt; ++jt) {
    *(short8*)&KV[srow][sdb] = kreg;
    const unsigned short* nsrc = (jt + 1 < njt)
        ? Qb + (size_t)((jt + 1) * 64 + srow) * DD + sdb
        : Vtb + (size_t)srow * SS + sdb;
    kreg = *(const short8*)nsrc;
    __syncthreads();

    short8 a0 = *(const short8*)&Qs[wr * 16 + fr][fq * 8];
    short8 a1 = *(const short8*)&Qs[wr * 16 + fr][32 + fq * 8];
    short8 b0 = *(const short8*)&KV[wc * 16 + fr][fq * 8];
    short8 b1 = *(const short8*)&KV[wc * 16 + fr][32 + fq * 8];
    f32x4 s0 = {};
    s0 = __builtin_amdgcn_mfma_f32_16x16x32_bf16(a0, b0, s0, 0, 0, 0);
    s0 = __builtin_amdgcn_mfma_f32_16x16x32_bf16(a1, b1, s0, 0, 0, 0);

    const int j = jt * 64 + wc * 16 + fr;
#pragma unroll
    for (int r = 0; r < 4; ++r) {
      const int row = wr * 16 + fq * 4 + r;
      sc_s[row][j] = (j < i0 + row) ? s0[r] * 0.125f : -1e30f;
    }
    __syncthreads();
  }
  *(short8*)&KV[srow][sdb] = kreg;   // V tile 0

  const int half = lane >> 5;
  const int ll = lane & 31;
  const int jb = ll << 3;
  for (int q = 0; q < 2; ++q) {
    const int r_i = w * 4 + q * 2 + half;
    const int gi = i0 + r_i;
    const float* rowp = &sc_s[r_i][0];
    float4 v0 = *(const float4*)(rowp + jb);
    float4 v1 = *(const float4*)(rowp + jb + 4);
    float sc[8] = {v0.x, v0.y, v0.z, v0.w, v1.x, v1.y, v1.z, v1.w};
#pragma unroll
    for (int c = 0; c < 8; ++c)
      if (jb + c >= jcap) sc[c] = -1e30f;

    float m1 = sc[0];
#pragma unroll
    for (int c = 1; c < 8; ++c) m1 = fmaxf(m1, sc[c]);
    m1 = half_max(m1);
    float p[8];
    float lsum = 0.0f;
#pragma unroll
    for (int c = 0; c < 8; ++c) {
      p[c] = __expf(sc[c] - m1);
      lsum += p[c];
    }

    float xs = lsum;
#pragma unroll
    for (int off = 1; off < 32; off <<= 1) {
      float y = __shfl_up(xs, off, 32);
      if (ll >= off) xs += y;
    }
    const float tot = __shfl(xs, 31, 32);
    const float inv = 1.0f / tot;
    float run = xs - lsum;

    float s2[8];
#pragma unroll
    for (int c = 0; c < 8; ++c) {
      run += p[c];
      float cum = run * inv;
      float dist = sqrtf(fmaxf((1.0f - cum) * (float)(gi - (jb + c)), 0.0f));
      float te = __expf(gneg * dist);
      te = fminf(fmaxf(te, 1e-5f), 1e5f);
      s2[c] = sc[c] * te;
    }

    float m2 = s2[0];
#pragma unroll
    for (int c = 1; c < 8; ++c) m2 = fmaxf(m2, s2[c]);
    m2 = half_max(m2);
    float e[8];
    float lsum2 = 0.0f;
#pragma unroll
    for (int c = 0; c < 8; ++c) {
      e[c] = __expf(s2[c] - m2);
      lsum2 += e[c];
    }
    const float tot2 = half_sum(lsum2);
    const float mult = fminf(tot2, 5.0f) / tot2;

    float av[8];
#pragma unroll
    for (int c = 0; c < 8; ++c) {
      av[c] = (gi == 0) ? 0.0f : e[c] * mult;
    }

    if (scores_out) {
      float* so = scores_out + ((size_t)(b * HH + h) * SS + gi) * SS + jb;
      *(float4*)(so) = make_float4(av[0], av[1], av[2], av[3]);
      *(float4*)(so + 4) = make_float4(av[4], av[5], av[6], av[7]);
      *(float4*)(so + 256) = make_float4(0.f, 0.f, 0.f, 0.f);
      *(float4*)(so + 260) = make_float4(0.f, 0.f, 0.f, 0.f);
    }

    short8 pk;
#pragma unroll
    for (int c = 0; c < 8; ++c) pk[c] = (short)f2bf(av[c]);
    *(short8*)((unsigned short*)&sc_s[r_i][0] + jb) = pk;
  }
  __syncthreads();

  short8 vreg;
  if (njt > 1) vreg = *(const short8*)(Vtb + (size_t)srow * SS + 64 + sdb);
  f32x4 o0 = {};
  for (int jt = 0; jt < njt; ++jt) {
    const unsigned short* arow = (const unsigned short*)&sc_s[wr * 16 + fr][0];
    short8 a0 = *(const short8*)(arow + jt * 64 + fq * 8);
    short8 a1 = *(const short8*)(arow + jt * 64 + 32 + fq * 8);
    short8 b0 = *(const short8*)&KV[wc * 16 + fr][fq * 8];
    short8 b1 = *(const short8*)&KV[wc * 16 + fr][32 + fq * 8];
    o0 = __builtin_amdgcn_mfma_f32_16x16x32_bf16(a0, b0, o0, 0, 0, 0);
    o0 = __builtin_amdgcn_mfma_f32_16x16x32_bf16(a1, b1, o0, 0, 0, 0);
    __syncthreads();
    if (jt + 1 < njt) {
      *(short8*)&KV[srow][sdb] = vreg;
      if (jt + 2 < njt) vreg = *(const short8*)(Vtb + (size_t)srow * SS + (jt + 2) * 64 + sdb);
      __syncthreads();
    }
  }

  {
    const int d = h * DHH + wc * 16 + fr;
#pragma unroll
    for (int r = 0; r < 4; ++r) {
      const int row = i0 + wr * 16 + fq * 4 + r;
      AO[((size_t)b * SS + row) * DD + d] = f2bf(o0[r]);
    }
  }
}

// ---------------- residual + layernorm (fp32 out, optional bf16 shadow) ----------------
__global__ __launch_bounds__(256) void k_res_ln(
    const float* __restrict__ x, const float* __restrict__ r,
    const float* __restrict__ w, const float* __restrict__ b,
    float* __restrict__ out, unsigned short* __restrict__ outb) {
  __shared__ float red[4];
  const int row = blockIdx.x;
  const int tid = threadIdx.x;
  const int lane = tid & 63, wv = tid >> 6;
  float4 y = ((const float4*)(x + (size_t)row * DD))[tid];
  if (r) {
    float4 rr = ((const float4*)(r + (size_t)row * DD))[tid];
    y.x += rr.x; y.y += rr.y; y.z += rr.z; y.w += rr.w;
  }
  float s = y.x + y.y + y.z + y.w;
  s = wave_sum(s);
  if (lane == 0) red[wv] = s;
  __syncthreads();
  float mean = (red[0] + red[1] + red[2] + red[3]) * (1.0f / DD);
  __syncthreads();
  float d0 = y.x - mean, d1 = y.y - mean, d2 = y.z - mean, d3 = y.w - mean;
  float s2 = d0 * d0 + d1 * d1 + d2 * d2 + d3 * d3;
  s2 = wave_sum(s2);
  if (lane == 0) red[wv] = s2;
  __syncthreads();
  float var = (red[0] + red[1] + red[2] + red[3]) * (1.0f / DD);
  float rstd = rsqrtf(var + 1e-5f);
  float4 ww = ((const float4*)w)[tid];
  float4 bb = ((const float4*)b)[tid];
  float4 o;
  o.x = d0 * rstd * ww.x + bb.x;
  o.y = d1 * rstd * ww.y + bb.y;
  o.z = d2 * rstd * ww.z + bb.z;
  o.w = d3 * rstd * ww.w + bb.w;
  ((float4*)(out + (size_t)row * DD))[tid] = o;
  if (outb) {
    uint2 pk;
    pk.x = (unsigned)f2bf(o.x) | ((unsigned)f2bf(o.y) << 16);
    pk.y = (unsigned)f2bf(o.z) | ((unsigned)f2bf(o.w) << 16);
    *(uint2*)(outb + (size_t)row * DD + tid * 4) = pk;
  }
}

extern "C" void kernel_launch(void* const* d_in, const int* in_sizes, int n_in,
                              void* d_out, int out_size, void* d_ws, size_t ws_size,
                              hipStream_t stream) {
  (void)in_sizes; (void)n_in; (void)out_size; (void)ws_size;
  const float* x = (const float*)d_in[0];
  const float* Wq = (const float*)d_in[2];
  const float* bq = (const float*)d_in[3];
  const float* Wv = (const float*)d_in[4];
  const float* bv = (const float*)d_in[5];
  const float* Wo = (const float*)d_in[6];
  const float* bo = (const float*)d_in[7];
  const float* gam = (const float*)d_in[8];
  const float* lnw = (const float*)d_in[9];
  const float* lnb = (const float*)d_in[10];
  const float* flnw = (const float*)d_in[11];
  const float* flnb = (const float*)d_in[12];

  float* out0 = (float*)d_out;
  float* scores = out0 + (size_t)BB * SS * DD;
  const size_t BUF = (size_t)BB * SS * DD;       // 8.4M elems
  const size_t WSZ = (size_t)LL * DD * DD;       // 4.2M elems per weight set
  const size_t BHSS = (size_t)BB * HH * SS * SS; // 67.1M floats (scores)

  float* P0 = (float*)d_ws;
  float* P1 = P0 + BUF;
  unsigned short* us = (unsigned short*)(P1 + BUF);
  unsigned short* Abf = us;
  unsigned short* Qbf = us + BUF;
  unsigned short* VtB = us + 2 * BUF;
  unsigned short* AObf = us + 3 * BUF;
  unsigned short* Wob = us + 4 * BUF;
  // Wqv bf16 ([L][2048][1024]) lives at the tail of the scores region:
  // last read (l=3 QV GEMM) precedes the l=3 attention that overwrites scores.
  unsigned short* Wqvb = (unsigned short*)scores + (2 * BHSS - 2 * WSZ);

  const int M = BB * SS;  // 8192

  k_w2bf_qv<<<dim3(2 * WSZ / 1024), 256, 0, stream>>>(Wq, Wv, Wqvb);
  k_w2bf<<<dim3(WSZ / 1024), 256, 0, stream>>>(Wo, Wob);
  k_add_pe<<<dim3(BUF / 1024), 256, 0, stream>>>(x, P0, Abf);

  float* Acur = P0;
  float* Pnx = P1;
  for (int l = 0; l < LL; ++l) {
    float* sc_dst = (l == LL - 1) ? scores : nullptr;
    k_gemm<3><<<dim3(1024), 256, 0, stream>>>(Abf, Wqvb + (size_t)l * 2048 * DD,
                                              bq + l * DD, bv + l * DD, Qbf, VtB);
    k_attn_small<<<dim3(BB * HH * 8), 512, 0, stream>>>(Qbf, VtB, gam + l * HH, AObf, sc_dst);
    k_attn_big<<<dim3(BB * HH * 8), 512, 0, stream>>>(Qbf, VtB, gam + l * HH, AObf, sc_dst);
    k_gemm<2><<<dim3(512), 256, 0, stream>>>(AObf, Wob + (size_t)l * DD * DD,
                                             bo + l * DD, nullptr, Pnx, nullptr);
    k_res_ln<<<dim3(M), 256, 0, stream>>>(Acur, Pnx, lnw + l * DD, lnb + l * DD, Pnx, Abf);
    float* t = Acur; Acur = Pnx; Pnx = t;
  }
  k_res_ln<<<dim3(M), 256, 0, stream>>>(Acur, nullptr, flnw, flnb, out0, nullptr);
}

// Round 10
// 913.812 us; speedup vs baseline: 1.5472x; 1.0321x over previous
//
#include <hip/hip_runtime.h>
#include <hip/hip_bf16.h>

#define BB 16
#define SS 512
#define DD 1024
#define HH 16
#define LL 4
#define DHH 64
#define GK 1024

typedef __attribute__((ext_vector_type(8))) short short8;
typedef __attribute__((ext_vector_type(4))) float f32x4;

__device__ __forceinline__ unsigned short f2bf(float f) {
  union { float f; unsigned int u; } v; v.f = f;
  unsigned int r = v.u + 0x7FFFu + ((v.u >> 16) & 1u);
  return (unsigned short)(r >> 16);
}

__device__ __forceinline__ float wave_max(float v) {
#pragma unroll
  for (int off = 32; off > 0; off >>= 1) v = fmaxf(v, __shfl_xor(v, off));
  return v;
}
__device__ __forceinline__ float wave_sum(float v) {
#pragma unroll
  for (int off = 32; off > 0; off >>= 1) v += __shfl_xor(v, off);
  return v;
}
__device__ __forceinline__ float half_max(float v) {   // width-32 segment
#pragma unroll
  for (int off = 16; off > 0; off >>= 1) v = fmaxf(v, __shfl_xor(v, off));
  return v;
}
__device__ __forceinline__ float half_sum(float v) {
#pragma unroll
  for (int off = 16; off > 0; off >>= 1) v += __shfl_xor(v, off);
  return v;
}

// global -> LDS direct 16B copy. LDS dest is wave-uniform base + lane*16.
__device__ __forceinline__ void gl16(const void* g, void* l) {
  __builtin_amdgcn_global_load_lds(
      (const __attribute__((address_space(1))) unsigned int*)(uintptr_t)g,
      (__attribute__((address_space(3))) unsigned int*)(unsigned int)(uintptr_t)l,
      16, 0, 0);
}

// ---------------- weights fp32 -> bf16 ----------------
__global__ __launch_bounds__(256) void k_w2bf_qv(const float* __restrict__ wq,
                                                 const float* __restrict__ wv,
                                                 unsigned short* __restrict__ o) {
  size_t i4 = ((size_t)blockIdx.x * 256 + threadIdx.x) * 4;
  size_t l = i4 >> 21;
  size_t r = i4 & ((1u << 21) - 1);
  const float* src = (r < (1u << 20)) ? wq + (l << 20) + r
                                      : wv + (l << 20) + (r - (1u << 20));
  float4 v = *(const float4*)src;
  uint2 pk;
  pk.x = (unsigned)f2bf(v.x) | ((unsigned)f2bf(v.y) << 16);
  pk.y = (unsigned)f2bf(v.z) | ((unsigned)f2bf(v.w) << 16);
  *(uint2*)(o + i4) = pk;
}
__global__ __launch_bounds__(256) void k_w2bf(const float* __restrict__ w,
                                              unsigned short* __restrict__ o) {
  size_t i4 = ((size_t)blockIdx.x * 256 + threadIdx.x) * 4;
  float4 v = *(const float4*)(w + i4);
  uint2 pk;
  pk.x = (unsigned)f2bf(v.x) | ((unsigned)f2bf(v.y) << 16);
  pk.y = (unsigned)f2bf(v.z) | ((unsigned)f2bf(v.w) << 16);
  *(uint2*)(o + i4) = pk;
}

// ---------------- q0 = x + positional encoding (fp32 + bf16 shadow) ----------------
__global__ __launch_bounds__(256) void k_add_pe(const float* __restrict__ x,
                                                float* __restrict__ out,
                                                unsigned short* __restrict__ outb) {
  size_t i4 = ((size_t)blockIdx.x * 256 + threadIdx.x) * 4;
  int d0 = (int)(i4 & (DD - 1));
  int s = (int)((i4 >> 10) & (SS - 1));
  float4 xv = *(const float4*)(x + i4);
  int ip0 = d0 >> 1;
  float f0 = __expf((float)ip0 * -0.017988946039016f);
  float f1 = __expf((float)(ip0 + 1) * -0.017988946039016f);
  float s0v, c0v, s1v, c1v;
  __sincosf((float)s * f0, &s0v, &c0v);
  __sincosf((float)s * f1, &s1v, &c1v);
  float4 o;
  o.x = xv.x + s0v; o.y = xv.y + c0v; o.z = xv.z + s1v; o.w = xv.w + c1v;
  *(float4*)(out + i4) = o;
  uint2 pk;
  pk.x = (unsigned)f2bf(o.x) | ((unsigned)f2bf(o.y) << 16);
  pk.y = (unsigned)f2bf(o.z) | ((unsigned)f2bf(o.w) << 16);
  *(uint2*)(outb + i4) = pk;
}

// ---------------- C = A[M,K]bf16 @ W[N,K]^T bf16 + bias ----------------
// 128x128 tile, 4 waves, BK=32, gl16 staging, 2-phase double-buffered LDS.
// MODE 0: bf16 [M,1024]. MODE 2: fp32 [M,1024].
// MODE 3: fused QV (N=2048): col<1024 -> bf16 Qbf; col>=1024 -> transposed VtB.
template <int MODE>
__global__ __launch_bounds__(256) void k_gemm(
    const unsigned short* __restrict__ A, const unsigned short* __restrict__ W,
    const float* __restrict__ bias, const float* __restrict__ bias2,
    void* __restrict__ out, void* __restrict__ out2) {
  __shared__ unsigned short As[2][128 * 32];
  __shared__ unsigned short Bs[2][128 * 32];
  const int tid = threadIdx.x;
  const int lane = tid & 63;
  const int w = tid >> 6;
  const int wr = w >> 1, wc = w & 1;
  const int fr = lane & 15, fq = lane >> 4;

  int bid = blockIdx.x;
  const int cpx = gridDim.x >> 3;
  bid = (bid & 7) * cpx + (bid >> 3);
  const int bm = (bid & 63) * 128;
  const int bn = (bid >> 6) * 128;

  f32x4 acc[4][4] = {};

  const unsigned short* ga = A + (size_t)(bm + w * 16 + (lane >> 2)) * GK + (lane & 3) * 8;
  const unsigned short* gb = W + (size_t)(bn + w * 16 + (lane >> 2)) * GK + (lane & 3) * 8;

  auto STAGE = [&](int buf, int k0) {
    unsigned short* la = As[buf] + w * 512;
    unsigned short* lb = Bs[buf] + w * 512;
    gl16(ga + k0, la);
    gl16(ga + 64 * GK + k0, la + 2048);
    gl16(gb + k0, lb);
    gl16(gb + 64 * GK + k0, lb + 2048);
  };

  STAGE(0, 0);
  __syncthreads();
  int cur = 0;
  for (int k0 = 0; k0 < GK; k0 += 32) {
    if (k0 + 32 < GK) STAGE(cur ^ 1, k0 + 32);
    short8 af[4], bf[4];
#pragma unroll
    for (int m = 0; m < 4; ++m)
      af[m] = *(const short8*)(As[cur] + (wr * 64 + m * 16 + fr) * 32 + fq * 8);
#pragma unroll
    for (int n = 0; n < 4; ++n)
      bf[n] = *(const short8*)(Bs[cur] + (wc * 64 + n * 16 + fr) * 32 + fq * 8);
#pragma unroll
    for (int m = 0; m < 4; ++m)
#pragma unroll
      for (int n = 0; n < 4; ++n)
        acc[m][n] = __builtin_amdgcn_mfma_f32_16x16x32_bf16(af[m], bf[n], acc[m][n], 0, 0, 0);
    __syncthreads();
    cur ^= 1;
  }

#pragma unroll
  for (int m = 0; m < 4; ++m) {
    const int row0 = bm + wr * 64 + m * 16 + fq * 4;
#pragma unroll
    for (int n = 0; n < 4; ++n) {
      const int col = bn + wc * 64 + n * 16 + fr;
      if constexpr (MODE == 0) {
        const float bsv = bias[col];
        unsigned short* o = (unsigned short*)out;
#pragma unroll
        for (int r = 0; r < 4; ++r)
          o[(size_t)(row0 + r) * DD + col] = f2bf(acc[m][n][r] + bsv);
      } else if constexpr (MODE == 2) {
        const float bsv = bias[col];
        float* o = (float*)out;
#pragma unroll
        for (int r = 0; r < 4; ++r)
          o[(size_t)(row0 + r) * DD + col] = acc[m][n][r] + bsv;
      } else {  // MODE 3: fused QV
        if (col < DD) {
          const float bsv = bias[col];
          unsigned short* o = (unsigned short*)out;
#pragma unroll
          for (int r = 0; r < 4; ++r)
            o[(size_t)(row0 + r) * DD + col] = f2bf(acc[m][n][r] + bsv);
        } else {
          const int c2 = col - DD;
          const float bsv = bias2[c2];
          unsigned short* o = (unsigned short*)out2;
          const int bi = row0 >> 9, si = row0 & (SS - 1);
          uint2 pk;
          pk.x = (unsigned)f2bf(acc[m][n][0] + bsv) | ((unsigned)f2bf(acc[m][n][1] + bsv) << 16);
          pk.y = (unsigned)f2bf(acc[m][n][2] + bsv) | ((unsigned)f2bf(acc[m][n][3] + bsv) << 16);
          *(uint2*)(o + ((size_t)bi * DD + c2) * SS + si) = pk;
        }
      }
    }
  }
}

// ---------------- fused MFMA attention, BIG half (itiles 8..15) ----------------
// softmax#1 is max-free (only cum/tot ratios used; scores bounded, fp32-safe).
// softmax#2 KEEPS the m2 max pass: the maxout rescale needs max(e)==1.
__global__ __launch_bounds__(512) void k_attn_big(
    const unsigned short* __restrict__ Q, const unsigned short* __restrict__ Vt,
    const float* __restrict__ gam, unsigned short* __restrict__ AO,
    float* __restrict__ scores_out) {
  __shared__ float sc_s[32][516];          // 66048 B
  __shared__ unsigned short Qs[32][72];    //  4608 B
  __shared__ unsigned short KV[64][72];    //  9216 B

  const int tid = threadIdx.x;
  const int lane = tid & 63;
  const int w = tid >> 6;
  const int wr = w & 1;
  const int wc = w >> 1;
  const int fr = lane & 15, fq = lane >> 4;

  const int itile = 8 + (blockIdx.x & 7);
  const int bh = blockIdx.x >> 3;
  const int b = bh >> 4;
  const int h = bh & 15;
  const int i0 = itile * 32;
  const int njt = (itile + 2) >> 1;        // 5..8
  const int jcap = njt * 64;

  const unsigned short* Qb = Q + (size_t)b * SS * DD + h * DHH;
  const unsigned short* Vtb = Vt + ((size_t)b * DD + h * DHH) * SS;
  const float gneg = -fabsf(gam[h]);

  const int srow = tid >> 3;
  const int sdb = (tid & 7) * 8;

  if (tid < 256) {
    const int qr = tid >> 3, qc = (tid & 7) * 8;
    *(short8*)&Qs[qr][qc] = *(const short8*)(Qb + (size_t)(i0 + qr) * DD + qc);
  }

  short8 kreg = *(const short8*)(Qb + (size_t)srow * DD + sdb);
  for (int jt = 0; jt < njt; ++jt) {
    *(short8*)&KV[srow][sdb] = kreg;
    const unsigned short* nsrc = (jt + 1 < njt)
        ? Qb + (size_t)((jt + 1) * 64 + srow) * DD + sdb
        : Vtb + (size_t)srow * SS + sdb;
    kreg = *(const short8*)nsrc;
    __syncthreads();

    short8 a0 = *(const short8*)&Qs[wr * 16 + fr][fq * 8];
    short8 a1 = *(const short8*)&Qs[wr * 16 + fr][32 + fq * 8];
    short8 b0 = *(const short8*)&KV[wc * 16 + fr][fq * 8];
    short8 b1 = *(const short8*)&KV[wc * 16 + fr][32 + fq * 8];
    f32x4 s0 = {};
    s0 = __builtin_amdgcn_mfma_f32_16x16x32_bf16(a0, b0, s0, 0, 0, 0);
    s0 = __builtin_amdgcn_mfma_f32_16x16x32_bf16(a1, b1, s0, 0, 0, 0);

    const int j = jt * 64 + wc * 16 + fr;
#pragma unroll
    for (int r = 0; r < 4; ++r) {
      const int row = wr * 16 + fq * 4 + r;
      sc_s[row][j] = (j < i0 + row) ? s0[r] * 0.125f : -1e30f;
    }
    __syncthreads();
  }
  *(short8*)&KV[srow][sdb] = kreg;   // V tile 0

  const int jb = lane << 3;
#pragma unroll 2
  for (int q = 0; q < 4; ++q) {
    const int r_i = w * 4 + q;
    const int gi = i0 + r_i;
    const float* rowp = &sc_s[r_i][0];
    float4 v0 = *(const float4*)(rowp + jb);
    float4 v1 = *(const float4*)(rowp + jb + 4);
    float sc[8] = {v0.x, v0.y, v0.z, v0.w, v1.x, v1.y, v1.z, v1.w};
#pragma unroll
    for (int c = 0; c < 8; ++c)
      if (jb + c >= jcap) sc[c] = -1e30f;

    // softmax#1: max-free (ratio-invariant)
    float p[8];
    float lsum = 0.0f;
#pragma unroll
    for (int c = 0; c < 8; ++c) {
      p[c] = __expf(sc[c]);              // masked -> 0
      lsum += p[c];
    }

    float xs = lsum;
#pragma unroll
    for (int off = 1; off < 64; off <<= 1) {
      float y = __shfl_up(xs, off);
      if (lane >= off) xs += y;
    }
    const float tot = __shfl(xs, 63);    // scan lane63 == row total
    const float inv = 1.0f / tot;
    float run = xs - lsum;

    float s2[8];
#pragma unroll
    for (int c = 0; c < 8; ++c) {
      run += p[c];
      float cum = run * inv;
      float dist = sqrtf(fmaxf((1.0f - cum) * (float)(gi - (jb + c)), 0.0f));
      float te = __expf(gneg * dist);
      te = fminf(fmaxf(te, 1e-5f), 1e5f);
      s2[c] = sc[c] * te;
    }

    // softmax#2: max REQUIRED (maxout scale = min(tot2,5) relies on max(e)==1)
    float m2 = s2[0];
#pragma unroll
    for (int c = 1; c < 8; ++c) m2 = fmaxf(m2, s2[c]);
    m2 = wave_max(m2);
    float e[8];
    float lsum2 = 0.0f;
#pragma unroll
    for (int c = 0; c < 8; ++c) {
      e[c] = __expf(s2[c] - m2);
      lsum2 += e[c];
    }
    float tot2 = wave_sum(lsum2);
    float mult = fminf(tot2, 5.0f) / tot2;

    float av[8];
#pragma unroll
    for (int c = 0; c < 8; ++c) {
      av[c] = (gi == 0) ? 0.0f : e[c] * mult;
    }

    if (scores_out) {
      float* so = scores_out + ((size_t)(b * HH + h) * SS + gi) * SS + jb;
      *(float4*)(so) = make_float4(av[0], av[1], av[2], av[3]);
      *(float4*)(so + 4) = make_float4(av[4], av[5], av[6], av[7]);
    }

    short8 pk;
#pragma unroll
    for (int c = 0; c < 8; ++c) pk[c] = (short)f2bf(av[c]);
    *(short8*)((unsigned short*)&sc_s[r_i][0] + jb) = pk;
  }
  __syncthreads();

  short8 vreg;
  if (njt > 1) vreg = *(const short8*)(Vtb + (size_t)srow * SS + 64 + sdb);
  f32x4 o0 = {};
  for (int jt = 0; jt < njt; ++jt) {
    const unsigned short* arow = (const unsigned short*)&sc_s[wr * 16 + fr][0];
    short8 a0 = *(const short8*)(arow + jt * 64 + fq * 8);
    short8 a1 = *(const short8*)(arow + jt * 64 + 32 + fq * 8);
    short8 b0 = *(const short8*)&KV[wc * 16 + fr][fq * 8];
    short8 b1 = *(const short8*)&KV[wc * 16 + fr][32 + fq * 8];
    o0 = __builtin_amdgcn_mfma_f32_16x16x32_bf16(a0, b0, o0, 0, 0, 0);
    o0 = __builtin_amdgcn_mfma_f32_16x16x32_bf16(a1, b1, o0, 0, 0, 0);
    __syncthreads();
    if (jt + 1 < njt) {
      *(short8*)&KV[srow][sdb] = vreg;
      if (jt + 2 < njt) vreg = *(const short8*)(Vtb + (size_t)srow * SS + (jt + 2) * 64 + sdb);
      __syncthreads();
    }
  }

  {
    const int d = h * DHH + wc * 16 + fr;
#pragma unroll
    for (int r = 0; r < 4; ++r) {
      const int row = i0 + wr * 16 + fq * 4 + r;
      AO[((size_t)b * SS + row) * DD + d] = f2bf(o0[r]);
    }
  }
}

// ---------------- fused MFMA attention, SMALL half (itiles 0..7) ----------------
__global__ __launch_bounds__(512) void k_attn_small(
    const unsigned short* __restrict__ Q, const unsigned short* __restrict__ Vt,
    const float* __restrict__ gam, unsigned short* __restrict__ AO,
    float* __restrict__ scores_out) {
  __shared__ float sc_s[32][260];          // 33280 B
  __shared__ unsigned short Qs[32][72];    //  4608 B
  __shared__ unsigned short KV[64][72];    //  9216 B => 47104 B

  const int tid = threadIdx.x;
  const int lane = tid & 63;
  const int w = tid >> 6;
  const int wr = w & 1;
  const int wc = w >> 1;
  const int fr = lane & 15, fq = lane >> 4;

  const int itile = blockIdx.x & 7;
  const int bh = blockIdx.x >> 3;
  const int b = bh >> 4;
  const int h = bh & 15;
  const int i0 = itile * 32;
  const int njt = (itile + 2) >> 1;        // 1..4
  const int jcap = njt * 64;

  const unsigned short* Qb = Q + (size_t)b * SS * DD + h * DHH;
  const unsigned short* Vtb = Vt + ((size_t)b * DD + h * DHH) * SS;
  const float gneg = -fabsf(gam[h]);

  const int srow = tid >> 3;
  const int sdb = (tid & 7) * 8;

  if (tid < 256) {
    const int qr = tid >> 3, qc = (tid & 7) * 8;
    *(short8*)&Qs[qr][qc] = *(const short8*)(Qb + (size_t)(i0 + qr) * DD + qc);
  }

  short8 kreg = *(const short8*)(Qb + (size_t)srow * DD + sdb);
  for (int jt = 0; jt < njt; ++jt) {
    *(short8*)&KV[srow][sdb] = kreg;
    const unsigned short* nsrc = (jt + 1 < njt)
        ? Qb + (size_t)((jt + 1) * 64 + srow) * DD + sdb
        : Vtb + (size_t)srow * SS + sdb;
    kreg = *(const short8*)nsrc;
    __syncthreads();

    short8 a0 = *(const short8*)&Qs[wr * 16 + fr][fq * 8];
    short8 a1 = *(const short8*)&Qs[wr * 16 + fr][32 + fq * 8];
    short8 b0 = *(const short8*)&KV[wc * 16 + fr][fq * 8];
    short8 b1 = *(const short8*)&KV[wc * 16 + fr][32 + fq * 8];
    f32x4 s0 = {};
    s0 = __builtin_amdgcn_mfma_f32_16x16x32_bf16(a0, b0, s0, 0, 0, 0);
    s0 = __builtin_amdgcn_mfma_f32_16x16x32_bf16(a1, b1, s0, 0, 0, 0);

    const int j = jt * 64 + wc * 16 + fr;
#pragma unroll
    for (int r = 0; r < 4; ++r) {
      const int row = wr * 16 + fq * 4 + r;
      sc_s[row][j] = (j < i0 + row) ? s0[r] * 0.125f : -1e30f;
    }
    __syncthreads();
  }
  *(short8*)&KV[srow][sdb] = kreg;   // V tile 0

  const int half = lane >> 5;
  const int ll = lane & 31;
  const int jb = ll << 3;
  for (int q = 0; q < 2; ++q) {
    const int r_i = w * 4 + q * 2 + half;
    const int gi = i0 + r_i;
    const float* rowp = &sc_s[r_i][0];
    float4 v0 = *(const float4*)(rowp + jb);
    float4 v1 = *(const float4*)(rowp + jb + 4);
    float sc[8] = {v0.x, v0.y, v0.z, v0.w, v1.x, v1.y, v1.z, v1.w};
#pragma unroll
    for (int c = 0; c < 8; ++c)
      if (jb + c >= jcap) sc[c] = -1e30f;

    // softmax#1: max-free
    float p[8];
    float lsum = 0.0f;
#pragma unroll
    for (int c = 0; c < 8; ++c) {
      p[c] = __expf(sc[c]);
      lsum += p[c];
    }

    float xs = lsum;
#pragma unroll
    for (int off = 1; off < 32; off <<= 1) {
      float y = __shfl_up(xs, off, 32);
      if (ll >= off) xs += y;
    }
    const float tot = __shfl(xs, 31, 32);
    const float inv = 1.0f / tot;
    float run = xs - lsum;

    float s2[8];
#pragma unroll
    for (int c = 0; c < 8; ++c) {
      run += p[c];
      float cum = run * inv;
      float dist = sqrtf(fmaxf((1.0f - cum) * (float)(gi - (jb + c)), 0.0f));
      float te = __expf(gneg * dist);
      te = fminf(fmaxf(te, 1e-5f), 1e5f);
      s2[c] = sc[c] * te;
    }

    // softmax#2: max required for maxout
    float m2 = s2[0];
#pragma unroll
    for (int c = 1; c < 8; ++c) m2 = fmaxf(m2, s2[c]);
    m2 = half_max(m2);
    float e[8];
    float lsum2 = 0.0f;
#pragma unroll
    for (int c = 0; c < 8; ++c) {
      e[c] = __expf(s2[c] - m2);
      lsum2 += e[c];
    }
    const float tot2 = half_sum(lsum2);
    const float mult = fminf(tot2, 5.0f) / tot2;

    float av[8];
#pragma unroll
    for (int c = 0; c < 8; ++c) {
      av[c] = (gi == 0) ? 0.0f : e[c] * mult;
    }

    if (scores_out) {
      float* so = scores_out + ((size_t)(b * HH + h) * SS + gi) * SS + jb;
      *(float4*)(so) = make_float4(av[0], av[1], av[2], av[3]);
      *(float4*)(so + 4) = make_float4(av[4], av[5], av[6], av[7]);
      *(float4*)(so + 256) = make_float4(0.f, 0.f, 0.f, 0.f);
      *(float4*)(so + 260) = make_float4(0.f, 0.f, 0.f, 0.f);
    }

    short8 pk;
#pragma unroll
    for (int c = 0; c < 8; ++c) pk[c] = (short)f2bf(av[c]);
    *(short8*)((unsigned short*)&sc_s[r_i][0] + jb) = pk;
  }
  __syncthreads();

  short8 vreg;
  if (njt > 1) vreg = *(const short8*)(Vtb + (size_t)srow * SS + 64 + sdb);
  f32x4 o0 = {};
  for (int jt = 0; jt < njt; ++jt) {
    const unsigned short* arow = (const unsigned short*)&sc_s[wr * 16 + fr][0];
    short8 a0 = *(const short8*)(arow + jt * 64 + fq * 8);
    short8 a1 = *(const short8*)(arow + jt * 64 + 32 + fq * 8);
    short8 b0 = *(const short8*)&KV[wc * 16 + fr][fq * 8];
    short8 b1 = *(const short8*)&KV[wc * 16 + fr][32 + fq * 8];
    o0 = __builtin_amdgcn_mfma_f32_16x16x32_bf16(a0, b0, o0, 0, 0, 0);
    o0 = __builtin_amdgcn_mfma_f32_16x16x32_bf16(a1, b1, o0, 0, 0, 0);
    __syncthreads();
    if (jt + 1 < njt) {
      *(short8*)&KV[srow][sdb] = vreg;
      if (jt + 2 < njt) vreg = *(const short8*)(Vtb + (size_t)srow * SS + (jt + 2) * 64 + sdb);
      __syncthreads();
    }
  }

  {
    const int d = h * DHH + wc * 16 + fr;
#pragma unroll
    for (int r = 0; r < 4; ++r) {
      const int row = i0 + wr * 16 + fq * 4 + r;
      AO[((size_t)b * SS + row) * DD + d] = f2bf(o0[r]);
    }
  }
}

// ---------------- residual + layernorm (fp32 out, optional bf16 shadow) ----------------
__global__ __launch_bounds__(256) void k_res_ln(
    const float* __restrict__ x, const float* __restrict__ r,
    const float* __restrict__ w, const float* __restrict__ b,
    float* __restrict__ out, unsigned short* __restrict__ outb) {
  __shared__ float red[4];
  const int row = blockIdx.x;
  const int tid = threadIdx.x;
  const int lane = tid & 63, wv = tid >> 6;
  float4 y = ((const float4*)(x + (size_t)row * DD))[tid];
  if (r) {
    float4 rr = ((const float4*)(r + (size_t)row * DD))[tid];
    y.x += rr.x; y.y += rr.y; y.z += rr.z; y.w += rr.w;
  }
  float s = y.x + y.y + y.z + y.w;
  s = wave_sum(s);
  if (lane == 0) red[wv] = s;
  __syncthreads();
  float mean = (red[0] + red[1] + red[2] + red[3]) * (1.0f / DD);
  __syncthreads();
  float d0 = y.x - mean, d1 = y.y - mean, d2 = y.z - mean, d3 = y.w - mean;
  float s2 = d0 * d0 + d1 * d1 + d2 * d2 + d3 * d3;
  s2 = wave_sum(s2);
  if (lane == 0) red[wv] = s2;
  __syncthreads();
  float var = (red[0] + red[1] + red[2] + red[3]) * (1.0f / DD);
  float rstd = rsqrtf(var + 1e-5f);
  float4 ww = ((const float4*)w)[tid];
  float4 bb = ((const float4*)b)[tid];
  float4 o;
  o.x = d0 * rstd * ww.x + bb.x;
  o.y = d1 * rstd * ww.y + bb.y;
  o.z = d2 * rstd * ww.z + bb.z;
  o.w = d3 * rstd * ww.w + bb.w;
  ((float4*)(out + (size_t)row * DD))[tid] = o;
  if (outb) {
    uint2 pk;
    pk.x = (unsigned)f2bf(o.x) | ((unsigned)f2bf(o.y) << 16);
    pk.y = (unsigned)f2bf(o.z) | ((unsigned)f2bf(o.w) << 16);
    *(uint2*)(outb + (size_t)row * DD + tid * 4) = pk;
  }
}

extern "C" void kernel_launch(void* const* d_in, const int* in_sizes, int n_in,
                              void* d_out, int out_size, void* d_ws, size_t ws_size,
                              hipStream_t stream) {
  (void)in_sizes; (void)n_in; (void)out_size; (void)ws_size;
  const float* x = (const float*)d_in[0];
  const float* Wq = (const float*)d_in[2];
  const float* bq = (const float*)d_in[3];
  const float* Wv = (const float*)d_in[4];
  const float* bv = (const float*)d_in[5];
  const float* Wo = (const float*)d_in[6];
  const float* bo = (const float*)d_in[7];
  const float* gam = (const float*)d_in[8];
  const float* lnw = (const float*)d_in[9];
  const float* lnb = (const float*)d_in[10];
  const float* flnw = (const float*)d_in[11];
  const float* flnb = (const float*)d_in[12];

  float* out0 = (float*)d_out;
  float* scores = out0 + (size_t)BB * SS * DD;
  const size_t BUF = (size_t)BB * SS * DD;
  const size_t WSZ = (size_t)LL * DD * DD;
  const size_t BHSS = (size_t)BB * HH * SS * SS;

  float* P0 = (float*)d_ws;
  float* P1 = P0 + BUF;
  unsigned short* us = (unsigned short*)(P1 + BUF);
  unsigned short* Abf = us;
  unsigned short* Qbf = us + BUF;
  unsigned short* VtB = us + 2 * BUF;
  unsigned short* AObf = us + 3 * BUF;
  unsigned short* Wob = us + 4 * BUF;
  unsigned short* Wqvb = (unsigned short*)scores + (2 * BHSS - 2 * WSZ);

  const int M = BB * SS;

  k_w2bf_qv<<<dim3(2 * WSZ / 1024), 256, 0, stream>>>(Wq, Wv, Wqvb);
  k_w2bf<<<dim3(WSZ / 1024), 256, 0, stream>>>(Wo, Wob);
  k_add_pe<<<dim3(BUF / 1024), 256, 0, stream>>>(x, P0, Abf);

  float* Acur = P0;
  float* Pnx = P1;
  for (int l = 0; l < LL; ++l) {
    float* sc_dst = (l == LL - 1) ? scores : nullptr;
    k_gemm<3><<<dim3(1024), 256, 0, stream>>>(Abf, Wqvb + (size_t)l * 2048 * DD,
                                              bq + l * DD, bv + l * DD, Qbf, VtB);
    k_attn_small<<<dim3(BB * HH * 8), 512, 0, stream>>>(Qbf, VtB, gam + l * HH, AObf, sc_dst);
    k_attn_big<<<dim3(BB * HH * 8), 512, 0, stream>>>(Qbf, VtB, gam + l * HH, AObf, sc_dst);
    k_gemm<2><<<dim3(512), 256, 0, stream>>>(AObf, Wob + (size_t)l * DD * DD,
                                             bo + l * DD, nullptr, Pnx, nullptr);
    k_res_ln<<<dim3(M), 256, 0, stream>>>(Acur, Pnx, lnw + l * DD, lnb + l * DD, Pnx, Abf);
    float* t = Acur; Acur = Pnx; Pnx = t;
  }
  k_res_ln<<<dim3(M), 256, 0, stream>>>(Acur, nullptr, flnw, flnb, out0, nullptr);
}